// Round 8
// baseline (1397.855 us; speedup 1.0000x reference)
//
#include <hip/hip_runtime.h>

#define N_NODES 100000
#define N_EDGES 1600000
#define B2_SHIFT 8
#define NB2 ((N_NODES + 255) >> 8)              // 391 buckets of 256 nodes
#define PAIR_EPB 2048                            // edges per k_pairs block
#define PAIR_BLOCKS ((N_EDGES + PAIR_EPB - 1) / PAIR_EPB)  // 782

// ============ histogram: per-node degree + per-bucket edge count ============
__global__ __launch_bounds__(256) void k_hist(const int* __restrict__ ei,
                                              int* __restrict__ cnt,
                                              int* __restrict__ bcnt)
{
    __shared__ int lh[NB2];
    for (int i = threadIdx.x; i < NB2; i += 256) lh[i] = 0;
    __syncthreads();
    int e = blockIdx.x * 256 + threadIdx.x;
    if (e < N_EDGES) {
        int dst = ei[N_EDGES + e];
        atomicAdd(&cnt[dst], 1);
        atomicAdd(&lh[dst >> B2_SHIFT], 1);
    }
    __syncthreads();
    for (int i = threadIdx.x; i < NB2; i += 256)
        if (lh[i]) atomicAdd(&bcnt[i], lh[i]);
}

// ============ scan 391 bucket counts (single block) ============
__global__ __launch_bounds__(512) void k_bscan(const int* __restrict__ bcnt,
                                               int* __restrict__ bbase,
                                               int* __restrict__ bcur)
{
    __shared__ int s[512];
    int v = (threadIdx.x < NB2) ? bcnt[threadIdx.x] : 0;
    s[threadIdx.x] = v;
    __syncthreads();
    for (int off = 1; off < 512; off <<= 1) {
        int t = (threadIdx.x >= off) ? s[threadIdx.x - off] : 0;
        __syncthreads();
        s[threadIdx.x] += t;
        __syncthreads();
    }
    if (threadIdx.x < NB2) {
        int ex = s[threadIdx.x] - v;
        bbase[threadIdx.x] = ex;
        bcur[threadIdx.x] = ex;
    }
    if (threadIdx.x == 0) bbase[NB2] = N_EDGES;
}

// ============ bucket edges: pairs[slot] = (src<<8) | (dst & 255) ============
__global__ __launch_bounds__(256) void k_pairs(const int* __restrict__ ei,
                                               int* __restrict__ bcur,
                                               int* __restrict__ pairs)
{
    __shared__ int lh[NB2];
    __shared__ int lbase[NB2];
    for (int i = threadIdx.x; i < NB2; i += 256) lh[i] = 0;
    __syncthreads();
    int base = blockIdx.x * PAIR_EPB;
    int myb[8], myr[8], myp[8];
#pragma unroll
    for (int t = 0; t < 8; t++) {
        int e = base + t * 256 + threadIdx.x;
        myb[t] = -1;
        if (e < N_EDGES) {
            int dst = ei[N_EDGES + e];
            int b = dst >> B2_SHIFT;
            myb[t] = b;
            myr[t] = atomicAdd(&lh[b], 1);
            myp[t] = (ei[e] << B2_SHIFT) | (dst & 255);
        }
    }
    __syncthreads();
    for (int i = threadIdx.x; i < NB2; i += 256)
        lbase[i] = lh[i] ? atomicAdd(&bcur[i], lh[i]) : 0;
    __syncthreads();
#pragma unroll
    for (int t = 0; t < 8; t++)
        if (myb[t] >= 0) pairs[lbase[myb[t]] + myr[t]] = myp[t];
}

// ============ layer-1 aggregation: LDS accumulate, one block per bucket =====
// 16 waves; lane = dim; each wave walks a strided slice of the bucket's pairs.
__global__ __launch_bounds__(1024) void k_agg1_lds(const int* __restrict__ bbase,
                                                   const int* __restrict__ pairs,
                                                   const float* __restrict__ x,
                                                   float* __restrict__ agg1)
{
    __shared__ float acc[256 * 64];   // 64 KB
    int b = blockIdx.x;
    {
        float4 z = make_float4(0.f, 0.f, 0.f, 0.f);
        float4* az = (float4*)acc;
        for (int i = threadIdx.x; i < 4096; i += 1024) az[i] = z;
    }
    __syncthreads();

    int beg = bbase[b], end = bbase[b + 1];
    int wid = threadIdx.x >> 6, lane = threadIdx.x & 63;
    int i = beg + wid * 4;
    for (; i + 4 <= end; i += 64) {       // 16 waves x 4 pairs
        int p0 = pairs[i + 0], p1 = pairs[i + 1];
        int p2 = pairs[i + 2], p3 = pairs[i + 3];
        float v0 = x[(size_t)(p0 >> 8) * 64 + lane];
        float v1 = x[(size_t)(p1 >> 8) * 64 + lane];
        float v2 = x[(size_t)(p2 >> 8) * 64 + lane];
        float v3 = x[(size_t)(p3 >> 8) * 64 + lane];
        atomicAdd(&acc[(p0 & 255) * 64 + lane], v0);
        atomicAdd(&acc[(p1 & 255) * 64 + lane], v1);
        atomicAdd(&acc[(p2 & 255) * 64 + lane], v2);
        atomicAdd(&acc[(p3 & 255) * 64 + lane], v3);
    }
    for (; i < end; i++) {                // tail (<4) for the straddling wave
        int p = pairs[i];
        atomicAdd(&acc[(p & 255) * 64 + lane], x[(size_t)(p >> 8) * 64 + lane]);
    }
    __syncthreads();

    int node0 = b << B2_SHIFT;
    for (int r = wid; r < 256; r += 16) {
        int n = node0 + r;
        if (n < N_NODES) agg1[(size_t)n * 64 + lane] = acc[r * 64 + lane];
    }
}

// ============ node transform: 4 threads/node, conflict-free LDS (R7) ========
#define W2S 36
__global__ __launch_bounds__(256, 3) void k_node(
    const float* __restrict__ x, const float* __restrict__ agg1,
    const int* __restrict__ cnt,
    const float* __restrict__ W1l, const float* __restrict__ b1l,
    const float* __restrict__ W1r, const float* __restrict__ W2l,
    const float* __restrict__ W2r,
    float* __restrict__ t2, float* __restrict__ t3)
{
    __shared__ float sW1l[64 * 64];
    __shared__ float sW1r[64 * 64];
    __shared__ float sW2l[64 * W2S];
    __shared__ float sW2r[64 * W2S];
    {
        float4* d1 = (float4*)sW1l; const float4* g1 = (const float4*)W1l;
        float4* d2 = (float4*)sW1r; const float4* g2 = (const float4*)W1r;
        for (int i = threadIdx.x; i < 1024; i += 256) { d1[i] = g1[i]; d2[i] = g2[i]; }
        const float4* g3 = (const float4*)W2l;
        const float4* g4 = (const float4*)W2r;
        for (int i = threadIdx.x; i < 512; i += 256) {
            int j = i >> 3, q = i & 7;
            *(float4*)(sW2l + j * W2S + q * 4) = g3[i];
            *(float4*)(sW2r + j * W2S + q * 4) = g4[i];
        }
    }
    __syncthreads();

    int t = blockIdx.x * 256 + threadIdx.x;
    int n = t >> 2;
    if (n >= N_NODES) return;
    int jg = t & 3;          // owns j = 16q + 4jg + e (q,e in 0..3)
    float inv = 1.0f / fmaxf((float)cnt[n], 1.0f);

    float acc[16];
    {
        const float4* bv = (const float4*)b1l;
#pragma unroll
        for (int q = 0; q < 4; q++) {
            float4 b4 = bv[4 * q + jg];
            acc[4*q+0] = b4.x; acc[4*q+1] = b4.y;
            acc[4*q+2] = b4.z; acc[4*q+3] = b4.w;
        }
    }

    const float4* av = (const float4*)(agg1 + (size_t)n * 64);
    const float4* xv = (const float4*)(x + (size_t)n * 64);
    for (int kk = 0; kk < 16; kk++) {
        float4 a4 = av[kk];
        float4 x4 = xv[kk];
        float as[4] = {a4.x * inv, a4.y * inv, a4.z * inv, a4.w * inv};
        float xs[4] = {x4.x, x4.y, x4.z, x4.w};
#pragma unroll
        for (int u = 0; u < 4; u++) {
            int k = kk * 4 + u;
            const float4* wlr = (const float4*)(sW1l + k * 64);
            const float4* wrr = (const float4*)(sW1r + k * 64);
#pragma unroll
            for (int q = 0; q < 4; q++) {
                float4 l4 = wlr[4 * q + jg], r4 = wrr[4 * q + jg];
                acc[4*q+0] += as[u] * l4.x + xs[u] * r4.x;
                acc[4*q+1] += as[u] * l4.y + xs[u] * r4.y;
                acc[4*q+2] += as[u] * l4.z + xs[u] * r4.z;
                acc[4*q+3] += as[u] * l4.w + xs[u] * r4.w;
            }
        }
    }

    float o2[32], o3[32];
#pragma unroll
    for (int o = 0; o < 32; o++) { o2[o] = 0.0f; o3[o] = 0.0f; }
#pragma unroll
    for (int q = 0; q < 4; q++) {
#pragma unroll
        for (int e = 0; e < 4; e++) {
            float hj = fmaxf(acc[4*q+e], 0.0f);
            int j = 16 * q + 4 * jg + e;
            const float4* w2 = (const float4*)(sW2l + j * W2S);
            const float4* w3 = (const float4*)(sW2r + j * W2S);
#pragma unroll
            for (int qq = 0; qq < 8; qq++) {
                float4 a = w2[qq], b = w3[qq];
                o2[4*qq+0] += hj * a.x;  o3[4*qq+0] += hj * b.x;
                o2[4*qq+1] += hj * a.y;  o3[4*qq+1] += hj * b.y;
                o2[4*qq+2] += hj * a.z;  o3[4*qq+2] += hj * b.z;
                o2[4*qq+3] += hj * a.w;  o3[4*qq+3] += hj * b.w;
            }
        }
    }
#pragma unroll
    for (int o = 0; o < 32; o++) {
        o2[o] += __shfl_xor(o2[o], 1);
        o2[o] += __shfl_xor(o2[o], 2);
        o3[o] += __shfl_xor(o3[o], 1);
        o3[o] += __shfl_xor(o3[o], 2);
    }
    float4* t2v = (float4*)(t2 + (size_t)n * 32 + jg * 8);
    float4* t3v = (float4*)(t3 + (size_t)n * 32 + jg * 8);
    if (jg == 0) {
        t2v[0] = make_float4(o2[0], o2[1], o2[2], o2[3]);
        t2v[1] = make_float4(o2[4], o2[5], o2[6], o2[7]);
        t3v[0] = make_float4(o3[0], o3[1], o3[2], o3[3]);
        t3v[1] = make_float4(o3[4], o3[5], o3[6], o3[7]);
    } else if (jg == 1) {
        t2v[0] = make_float4(o2[8], o2[9], o2[10], o2[11]);
        t2v[1] = make_float4(o2[12], o2[13], o2[14], o2[15]);
        t3v[0] = make_float4(o3[8], o3[9], o3[10], o3[11]);
        t3v[1] = make_float4(o3[12], o3[13], o3[14], o3[15]);
    } else if (jg == 2) {
        t2v[0] = make_float4(o2[16], o2[17], o2[18], o2[19]);
        t2v[1] = make_float4(o2[20], o2[21], o2[22], o2[23]);
        t3v[0] = make_float4(o3[16], o3[17], o3[18], o3[19]);
        t3v[1] = make_float4(o3[20], o3[21], o3[22], o3[23]);
    } else {
        t2v[0] = make_float4(o2[24], o2[25], o2[26], o2[27]);
        t2v[1] = make_float4(o2[28], o2[29], o2[30], o2[31]);
        t3v[0] = make_float4(o3[24], o3[25], o3[26], o3[27]);
        t3v[1] = make_float4(o3[28], o3[29], o3[30], o3[31]);
    }
}

// ============ layer-2 aggregation + output: LDS accumulate, fused epilogue ==
// 32 half-wave groups (g = tid>>5), d = tid&31; out = acc/deg + t3 + b2l.
__global__ __launch_bounds__(1024) void k_agg2_lds(const int* __restrict__ bbase,
                                                   const int* __restrict__ pairs,
                                                   const float* __restrict__ t2,
                                                   const float* __restrict__ t3,
                                                   const int* __restrict__ cnt,
                                                   const float* __restrict__ b2l,
                                                   float* __restrict__ out)
{
    __shared__ float acc[256 * 32];   // 32 KB
    int b = blockIdx.x;
    {
        float4 z = make_float4(0.f, 0.f, 0.f, 0.f);
        float4* az = (float4*)acc;
        for (int i = threadIdx.x; i < 2048; i += 1024) az[i] = z;
    }
    __syncthreads();

    int beg = bbase[b], end = bbase[b + 1];
    int g = threadIdx.x >> 5, d = threadIdx.x & 31;
    int i = beg + g * 4;
    for (; i + 4 <= end; i += 128) {      // 32 groups x 4 pairs
        int p0 = pairs[i + 0], p1 = pairs[i + 1];
        int p2 = pairs[i + 2], p3 = pairs[i + 3];
        float v0 = t2[(size_t)(p0 >> 8) * 32 + d];
        float v1 = t2[(size_t)(p1 >> 8) * 32 + d];
        float v2 = t2[(size_t)(p2 >> 8) * 32 + d];
        float v3 = t2[(size_t)(p3 >> 8) * 32 + d];
        atomicAdd(&acc[(p0 & 255) * 32 + d], v0);
        atomicAdd(&acc[(p1 & 255) * 32 + d], v1);
        atomicAdd(&acc[(p2 & 255) * 32 + d], v2);
        atomicAdd(&acc[(p3 & 255) * 32 + d], v3);
    }
    for (; i < end; i++) {
        int p = pairs[i];
        atomicAdd(&acc[(p & 255) * 32 + d], t2[(size_t)(p >> 8) * 32 + d]);
    }
    __syncthreads();

    int node0 = b << B2_SHIFT;
    float bias = b2l[d];
    for (int r = g; r < 256; r += 32) {
        int n = node0 + r;
        if (n < N_NODES) {
            float inv = 1.0f / fmaxf((float)cnt[n], 1.0f);
            out[(size_t)n * 32 + d] =
                acc[r * 32 + d] * inv + t3[(size_t)n * 32 + d] + bias;
        }
    }
}

extern "C" void kernel_launch(void* const* d_in, const int* in_sizes, int n_in,
                              void* d_out, int out_size, void* d_ws, size_t ws_size,
                              hipStream_t stream) {
    const float* x   = (const float*)d_in[0];
    const int*   ei  = (const int*)d_in[1];
    const float* W1l = (const float*)d_in[2];
    const float* b1l = (const float*)d_in[3];
    const float* W1r = (const float*)d_in[4];
    const float* W2l = (const float*)d_in[5];
    const float* b2l = (const float*)d_in[6];
    const float* W2r = (const float*)d_in[7];
    float* out = (float*)d_out;

    const size_t N = N_NODES, E = N_EDGES;
    int* wsi = (int*)d_ws;
    int* cnt   = wsi;                    // N      (zeroed)
    int* bcnt  = wsi + N;                // NB2    (zeroed, contiguous w/ cnt)
    int* bbase = wsi + N + NB2;          // NB2+1
    int* bcur  = wsi + N + 2 * NB2 + 1;  // NB2
    int* pairs = wsi + N + 3 * NB2 + 1;  // E
    float* wsf = (float*)(pairs + E);
    float* agg1 = wsf;                   // 64N
    float* t2   = wsf + 64 * N;          // 32N
    float* t3   = wsf + 96 * N;          // 32N
    // total ~= (N+3*NB2+1+E)*4 + 128N*4 ~= 58 MB

    hipMemsetAsync(cnt, 0, (N + NB2) * sizeof(int), stream);
    k_hist <<<(E + 255) / 256, 256, 0, stream>>>(ei, cnt, bcnt);
    k_bscan<<<1, 512, 0, stream>>>(bcnt, bbase, bcur);
    k_pairs<<<PAIR_BLOCKS, 256, 0, stream>>>(ei, bcur, pairs);

    k_agg1_lds<<<NB2, 1024, 0, stream>>>(bbase, pairs, x, agg1);
    k_node    <<<(int)((N * 4 + 255) / 256), 256, 0, stream>>>(x, agg1, cnt,
                                               W1l, b1l, W1r, W2l, W2r, t2, t3);
    k_agg2_lds<<<NB2, 1024, 0, stream>>>(bbase, pairs, t2, t3, cnt, b2l, out);
}

// Round 9
// 476.504 us; speedup vs baseline: 2.9336x; 2.9336x over previous
//
#include <hip/hip_runtime.h>

#define N_NODES 100000
#define N_EDGES 1600000
#define B2_SHIFT 8
#define NB2 ((N_NODES + 255) >> 8)              // 391 buckets of 256 nodes
#define PAIR_EPB 2048
#define PAIR_BLOCKS ((N_EDGES + PAIR_EPB - 1) / PAIR_EPB)  // 782

// ============ bucket histogram only (no per-node atomics) ============
__global__ __launch_bounds__(256) void k_hist(const int* __restrict__ ei,
                                              int* __restrict__ bcnt)
{
    __shared__ int lh[NB2];
    for (int i = threadIdx.x; i < NB2; i += 256) lh[i] = 0;
    __syncthreads();
    int e = blockIdx.x * 256 + threadIdx.x;
    if (e < N_EDGES) atomicAdd(&lh[ei[N_EDGES + e] >> B2_SHIFT], 1);
    __syncthreads();
    for (int i = threadIdx.x; i < NB2; i += 256)
        if (lh[i]) atomicAdd(&bcnt[i], lh[i]);
}

// ============ scan 391 bucket counts (single block) ============
__global__ __launch_bounds__(512) void k_bscan(const int* __restrict__ bcnt,
                                               int* __restrict__ bbase,
                                               int* __restrict__ bcur,
                                               int* __restrict__ row_start)
{
    __shared__ int s[512];
    int v = (threadIdx.x < NB2) ? bcnt[threadIdx.x] : 0;
    s[threadIdx.x] = v;
    __syncthreads();
    for (int off = 1; off < 512; off <<= 1) {
        int t = (threadIdx.x >= off) ? s[threadIdx.x - off] : 0;
        __syncthreads();
        s[threadIdx.x] += t;
        __syncthreads();
    }
    if (threadIdx.x < NB2) {
        int ex = s[threadIdx.x] - v;
        bbase[threadIdx.x] = ex;
        bcur[threadIdx.x] = ex;
    }
    if (threadIdx.x == 0) { bbase[NB2] = N_EDGES; row_start[N_NODES] = N_EDGES; }
}

// ============ bucket edges: pairs[slot] = (src<<8) | (dst & 255) ============
__global__ __launch_bounds__(256) void k_pairs(const int* __restrict__ ei,
                                               int* __restrict__ bcur,
                                               int* __restrict__ pairs)
{
    __shared__ int lh[NB2];
    __shared__ int lbase[NB2];
    for (int i = threadIdx.x; i < NB2; i += 256) lh[i] = 0;
    __syncthreads();
    int base = blockIdx.x * PAIR_EPB;
    int myb[8], myr[8], myp[8];
#pragma unroll
    for (int t = 0; t < 8; t++) {
        int e = base + t * 256 + threadIdx.x;
        myb[t] = -1;
        if (e < N_EDGES) {
            int dst = ei[N_EDGES + e];
            int b = dst >> B2_SHIFT;
            myb[t] = b;
            myr[t] = atomicAdd(&lh[b], 1);
            myp[t] = (ei[e] << B2_SHIFT) | (dst & 255);
        }
    }
    __syncthreads();
    for (int i = threadIdx.x; i < NB2; i += 256)
        lbase[i] = lh[i] ? atomicAdd(&bcur[i], lh[i]) : 0;
    __syncthreads();
#pragma unroll
    for (int t = 0; t < 8; t++)
        if (myb[t] >= 0) pairs[lbase[myb[t]] + myr[t]] = myp[t];
}

// ============ per-bucket CSR finalize: local hist+scan+scatter ============
// One block per bucket; its 16 KB sorted_src window is written by this block
// only (single-XCD line ownership). Emits row_start for its 256 nodes.
__global__ __launch_bounds__(256) void k_sortb(const int* __restrict__ bbase,
                                               const int* __restrict__ pairs,
                                               int* __restrict__ sorted_src,
                                               int* __restrict__ row_start)
{
    __shared__ int lcnt[256];
    __shared__ int lofs[256];
    int b = blockIdx.x;
    int beg = bbase[b], end = bbase[b + 1];
    lcnt[threadIdx.x] = 0;
    __syncthreads();
    for (int i = beg + threadIdx.x; i < end; i += 256)
        atomicAdd(&lcnt[pairs[i] & 255], 1);
    __syncthreads();
    int v = lcnt[threadIdx.x];
    lofs[threadIdx.x] = v;
    __syncthreads();
    for (int off = 1; off < 256; off <<= 1) {
        int t = (threadIdx.x >= off) ? lofs[threadIdx.x - off] : 0;
        __syncthreads();
        lofs[threadIdx.x] += t;
        __syncthreads();
    }
    int excl = lofs[threadIdx.x] - v;
    int n = (b << B2_SHIFT) + threadIdx.x;
    if (n < N_NODES) row_start[n] = beg + excl;
    lcnt[threadIdx.x] = excl;            // reuse as cursor
    __syncthreads();
    for (int i = beg + threadIdx.x; i < end; i += 256) {
        int p = pairs[i];
        int idx = atomicAdd(&lcnt[p & 255], 1);
        sorted_src[beg + idx] = p >> B2_SHIFT;
    }
}

// ============ agg1: wave per node, lane = dim (R7, proven) ============
__global__ __launch_bounds__(256) void k_agg1(const int* __restrict__ row_start,
                                              const int* __restrict__ sorted_src,
                                              const float* __restrict__ x,
                                              float* __restrict__ agg1)
{
    int node = blockIdx.x * 4 + (threadIdx.x >> 6);
    if (node >= N_NODES) return;
    int d = threadIdx.x & 63;
    int beg = row_start[node], end = row_start[node + 1];
    float a0 = 0.0f, a1 = 0.0f;
    int idx = beg;
    for (; idx + 2 <= end; idx += 2) {
        int s0 = sorted_src[idx];
        int s1 = sorted_src[idx + 1];
        a0 += x[(size_t)s0 * 64 + d];
        a1 += x[(size_t)s1 * 64 + d];
    }
    if (idx < end) a0 += x[(size_t)sorted_src[idx] * 64 + d];
    agg1[(size_t)node * 64 + d] = a0 + a1;
}

// ============ node transform: 4 threads/node, conflict-free LDS (R7) ========
#define W2S 36
__global__ __launch_bounds__(256, 3) void k_node(
    const float* __restrict__ x, const float* __restrict__ agg1,
    const int* __restrict__ row_start,
    const float* __restrict__ W1l, const float* __restrict__ b1l,
    const float* __restrict__ W1r, const float* __restrict__ W2l,
    const float* __restrict__ W2r,
    float* __restrict__ t2, float* __restrict__ t3)
{
    __shared__ float sW1l[64 * 64];
    __shared__ float sW1r[64 * 64];
    __shared__ float sW2l[64 * W2S];
    __shared__ float sW2r[64 * W2S];
    {
        float4* d1 = (float4*)sW1l; const float4* g1 = (const float4*)W1l;
        float4* d2 = (float4*)sW1r; const float4* g2 = (const float4*)W1r;
        for (int i = threadIdx.x; i < 1024; i += 256) { d1[i] = g1[i]; d2[i] = g2[i]; }
        const float4* g3 = (const float4*)W2l;
        const float4* g4 = (const float4*)W2r;
        for (int i = threadIdx.x; i < 512; i += 256) {
            int j = i >> 3, q = i & 7;
            *(float4*)(sW2l + j * W2S + q * 4) = g3[i];
            *(float4*)(sW2r + j * W2S + q * 4) = g4[i];
        }
    }
    __syncthreads();

    int t = blockIdx.x * 256 + threadIdx.x;
    int n = t >> 2;
    if (n >= N_NODES) return;
    int jg = t & 3;          // owns j = 16q + 4jg + e (q,e in 0..3)
    float degf = (float)(row_start[n + 1] - row_start[n]);
    float inv = 1.0f / fmaxf(degf, 1.0f);

    float acc[16];
    {
        const float4* bv = (const float4*)b1l;
#pragma unroll
        for (int q = 0; q < 4; q++) {
            float4 b4 = bv[4 * q + jg];
            acc[4*q+0] = b4.x; acc[4*q+1] = b4.y;
            acc[4*q+2] = b4.z; acc[4*q+3] = b4.w;
        }
    }

    const float4* av = (const float4*)(agg1 + (size_t)n * 64);
    const float4* xv = (const float4*)(x + (size_t)n * 64);
    for (int kk = 0; kk < 16; kk++) {
        float4 a4 = av[kk];
        float4 x4 = xv[kk];
        float as[4] = {a4.x * inv, a4.y * inv, a4.z * inv, a4.w * inv};
        float xs[4] = {x4.x, x4.y, x4.z, x4.w};
#pragma unroll
        for (int u = 0; u < 4; u++) {
            int k = kk * 4 + u;
            const float4* wlr = (const float4*)(sW1l + k * 64);
            const float4* wrr = (const float4*)(sW1r + k * 64);
#pragma unroll
            for (int q = 0; q < 4; q++) {
                float4 l4 = wlr[4 * q + jg], r4 = wrr[4 * q + jg];
                acc[4*q+0] += as[u] * l4.x + xs[u] * r4.x;
                acc[4*q+1] += as[u] * l4.y + xs[u] * r4.y;
                acc[4*q+2] += as[u] * l4.z + xs[u] * r4.z;
                acc[4*q+3] += as[u] * l4.w + xs[u] * r4.w;
            }
        }
    }

    float o2[32], o3[32];
#pragma unroll
    for (int o = 0; o < 32; o++) { o2[o] = 0.0f; o3[o] = 0.0f; }
#pragma unroll
    for (int q = 0; q < 4; q++) {
#pragma unroll
        for (int e = 0; e < 4; e++) {
            float hj = fmaxf(acc[4*q+e], 0.0f);
            int j = 16 * q + 4 * jg + e;
            const float4* w2 = (const float4*)(sW2l + j * W2S);
            const float4* w3 = (const float4*)(sW2r + j * W2S);
#pragma unroll
            for (int qq = 0; qq < 8; qq++) {
                float4 a = w2[qq], b = w3[qq];
                o2[4*qq+0] += hj * a.x;  o3[4*qq+0] += hj * b.x;
                o2[4*qq+1] += hj * a.y;  o3[4*qq+1] += hj * b.y;
                o2[4*qq+2] += hj * a.z;  o3[4*qq+2] += hj * b.z;
                o2[4*qq+3] += hj * a.w;  o3[4*qq+3] += hj * b.w;
            }
        }
    }
#pragma unroll
    for (int o = 0; o < 32; o++) {
        o2[o] += __shfl_xor(o2[o], 1);
        o2[o] += __shfl_xor(o2[o], 2);
        o3[o] += __shfl_xor(o3[o], 1);
        o3[o] += __shfl_xor(o3[o], 2);
    }
    float4* t2v = (float4*)(t2 + (size_t)n * 32 + jg * 8);
    float4* t3v = (float4*)(t3 + (size_t)n * 32 + jg * 8);
    if (jg == 0) {
        t2v[0] = make_float4(o2[0], o2[1], o2[2], o2[3]);
        t2v[1] = make_float4(o2[4], o2[5], o2[6], o2[7]);
        t3v[0] = make_float4(o3[0], o3[1], o3[2], o3[3]);
        t3v[1] = make_float4(o3[4], o3[5], o3[6], o3[7]);
    } else if (jg == 1) {
        t2v[0] = make_float4(o2[8], o2[9], o2[10], o2[11]);
        t2v[1] = make_float4(o2[12], o2[13], o2[14], o2[15]);
        t3v[0] = make_float4(o3[8], o3[9], o3[10], o3[11]);
        t3v[1] = make_float4(o3[12], o3[13], o3[14], o3[15]);
    } else if (jg == 2) {
        t2v[0] = make_float4(o2[16], o2[17], o2[18], o2[19]);
        t2v[1] = make_float4(o2[20], o2[21], o2[22], o2[23]);
        t3v[0] = make_float4(o3[16], o3[17], o3[18], o3[19]);
        t3v[1] = make_float4(o3[20], o3[21], o3[22], o3[23]);
    } else {
        t2v[0] = make_float4(o2[24], o2[25], o2[26], o2[27]);
        t2v[1] = make_float4(o2[28], o2[29], o2[30], o2[31]);
        t3v[0] = make_float4(o3[24], o3[25], o3[26], o3[27]);
        t3v[1] = make_float4(o3[28], o3[29], o3[30], o3[31]);
    }
}

// ============ fused agg2 + output (R7, proven) ============
__global__ __launch_bounds__(256) void k_agg2out(
    const int* __restrict__ row_start, const int* __restrict__ sorted_src,
    const float* __restrict__ t2, const float* __restrict__ t3,
    const float* __restrict__ b2l, float* __restrict__ out)
{
    int node = blockIdx.x * 8 + (threadIdx.x >> 5);
    if (node >= N_NODES) return;
    int d = threadIdx.x & 31;
    int beg = row_start[node], end = row_start[node + 1];
    float a0 = 0.0f, a1 = 0.0f;
    int idx = beg;
    for (; idx + 2 <= end; idx += 2) {
        int s0 = sorted_src[idx];
        int s1 = sorted_src[idx + 1];
        a0 += t2[(size_t)s0 * 32 + d];
        a1 += t2[(size_t)s1 * 32 + d];
    }
    if (idx < end) a0 += t2[(size_t)sorted_src[idx] * 32 + d];
    float deg = (float)(end - beg);
    float inv = 1.0f / fmaxf(deg, 1.0f);
    out[(size_t)node * 32 + d] = (a0 + a1) * inv + t3[(size_t)node * 32 + d] + b2l[d];
}

extern "C" void kernel_launch(void* const* d_in, const int* in_sizes, int n_in,
                              void* d_out, int out_size, void* d_ws, size_t ws_size,
                              hipStream_t stream) {
    const float* x   = (const float*)d_in[0];
    const int*   ei  = (const int*)d_in[1];
    const float* W1l = (const float*)d_in[2];
    const float* b1l = (const float*)d_in[3];
    const float* W1r = (const float*)d_in[4];
    const float* W2l = (const float*)d_in[5];
    const float* b2l = (const float*)d_in[6];
    const float* W2r = (const float*)d_in[7];
    float* out = (float*)d_out;

    const size_t N = N_NODES, E = N_EDGES;
    int* wsi = (int*)d_ws;
    int* bcnt       = wsi;                       // NB2  (zeroed)
    int* bbase      = wsi + NB2;                 // NB2+1
    int* bcur       = wsi + 2 * NB2 + 1;         // NB2
    int* row_start  = wsi + 3 * NB2 + 1;         // N+1
    int* pairs      = wsi + 3 * NB2 + 2 + N;     // E
    int* sorted_src = wsi + 3 * NB2 + 2 + N + E; // E
    float* wsf = (float*)(sorted_src + E);
    float* agg1 = wsf;                           // 64N
    float* t2   = wsf + 64 * N;                  // 32N
    float* t3   = wsf + 96 * N;                  // 32N
    // total ~= (3*NB2+2+N+2E)*4 + 128N*4 ~= 65 MB

    hipMemsetAsync(bcnt, 0, NB2 * sizeof(int), stream);
    k_hist <<<(E + 255) / 256, 256, 0, stream>>>(ei, bcnt);
    k_bscan<<<1, 512, 0, stream>>>(bcnt, bbase, bcur, row_start);
    k_pairs<<<PAIR_BLOCKS, 256, 0, stream>>>(ei, bcur, pairs);
    k_sortb<<<NB2, 256, 0, stream>>>(bbase, pairs, sorted_src, row_start);

    k_agg1   <<<(int)(N / 4), 256, 0, stream>>>(row_start, sorted_src, x, agg1);
    k_node   <<<(int)((N * 4 + 255) / 256), 256, 0, stream>>>(x, agg1, row_start,
                                                W1l, b1l, W1r, W2l, W2r, t2, t3);
    k_agg2out<<<(int)(N / 8), 256, 0, stream>>>(row_start, sorted_src, t2, t3, b2l, out);
}

// Round 10
// 363.625 us; speedup vs baseline: 3.8442x; 1.3104x over previous
//
#include <hip/hip_runtime.h>

#define N_NODES 100000
#define N_EDGES 1600000
#define B2_SHIFT 9
#define BUCK_N (1 << B2_SHIFT)                   // 512 nodes per bucket
#define NB2 ((N_NODES + BUCK_N - 1) >> B2_SHIFT) // 196 buckets
#define HIST_EPB 8192
#define HIST_BLOCKS ((N_EDGES + HIST_EPB - 1) / HIST_EPB)   // 196
#define PAIR_EPB 2048
#define PAIR_BLOCKS ((N_EDGES + PAIR_EPB - 1) / PAIR_EPB)   // 782

// ============ bucket histogram: chunked, few flush atomics ============
__global__ __launch_bounds__(256) void k_hist(const int* __restrict__ ei,
                                              int* __restrict__ bcnt)
{
    __shared__ int lh[NB2];
    for (int i = threadIdx.x; i < NB2; i += 256) lh[i] = 0;
    __syncthreads();
    int base = blockIdx.x * HIST_EPB;
#pragma unroll 4
    for (int t = 0; t < HIST_EPB / 256; t++) {
        int e = base + t * 256 + threadIdx.x;
        if (e < N_EDGES) atomicAdd(&lh[ei[N_EDGES + e] >> B2_SHIFT], 1);
    }
    __syncthreads();
    for (int i = threadIdx.x; i < NB2; i += 256)
        if (lh[i]) atomicAdd(&bcnt[i], lh[i]);
}

// ============ scan 196 bucket counts (single block) ============
__global__ __launch_bounds__(256) void k_bscan(const int* __restrict__ bcnt,
                                               int* __restrict__ bbase,
                                               int* __restrict__ bcur,
                                               int* __restrict__ row_start)
{
    __shared__ int s[256];
    int v = (threadIdx.x < NB2) ? bcnt[threadIdx.x] : 0;
    s[threadIdx.x] = v;
    __syncthreads();
    for (int off = 1; off < 256; off <<= 1) {
        int t = (threadIdx.x >= off) ? s[threadIdx.x - off] : 0;
        __syncthreads();
        s[threadIdx.x] += t;
        __syncthreads();
    }
    if (threadIdx.x < NB2) {
        int ex = s[threadIdx.x] - v;
        bbase[threadIdx.x] = ex;
        bcur[threadIdx.x] = ex;
    }
    if (threadIdx.x == 0) { bbase[NB2] = N_EDGES; row_start[N_NODES] = N_EDGES; }
}

// ============ bucket edges: pairs[slot] = (src<<9) | (dst & 511) ============
__global__ __launch_bounds__(256) void k_pairs(const int* __restrict__ ei,
                                               int* __restrict__ bcur,
                                               int* __restrict__ pairs)
{
    __shared__ int lh[NB2];
    __shared__ int lbase[NB2];
    for (int i = threadIdx.x; i < NB2; i += 256) lh[i] = 0;
    __syncthreads();
    int base = blockIdx.x * PAIR_EPB;
    int myb[8], myr[8], myp[8];
#pragma unroll
    for (int t = 0; t < 8; t++) {
        int e = base + t * 256 + threadIdx.x;
        myb[t] = -1;
        if (e < N_EDGES) {
            int dst = ei[N_EDGES + e];
            int b = dst >> B2_SHIFT;
            myb[t] = b;
            myr[t] = atomicAdd(&lh[b], 1);
            myp[t] = (ei[e] << B2_SHIFT) | (dst & (BUCK_N - 1));
        }
    }
    __syncthreads();
    for (int i = threadIdx.x; i < NB2; i += 256)
        lbase[i] = lh[i] ? atomicAdd(&bcur[i], lh[i]) : 0;
    __syncthreads();
#pragma unroll
    for (int t = 0; t < 8; t++)
        if (myb[t] >= 0) pairs[lbase[myb[t]] + myr[t]] = myp[t];
}

// ============ per-bucket CSR finalize: local hist+scan+scatter ============
// One block per bucket; its 32 KB sorted_src window is written only by this
// block. Emits row_start for its 512 nodes.
__global__ __launch_bounds__(512) void k_sortb(const int* __restrict__ bbase,
                                               const int* __restrict__ pairs,
                                               int* __restrict__ sorted_src,
                                               int* __restrict__ row_start)
{
    __shared__ int lcnt[BUCK_N];
    __shared__ int lofs[BUCK_N];
    int b = blockIdx.x;
    int beg = bbase[b], end = bbase[b + 1];
    lcnt[threadIdx.x] = 0;
    __syncthreads();
    for (int i = beg + threadIdx.x; i < end; i += 512)
        atomicAdd(&lcnt[pairs[i] & (BUCK_N - 1)], 1);
    __syncthreads();
    int v = lcnt[threadIdx.x];
    lofs[threadIdx.x] = v;
    __syncthreads();
    for (int off = 1; off < BUCK_N; off <<= 1) {
        int t = (threadIdx.x >= off) ? lofs[threadIdx.x - off] : 0;
        __syncthreads();
        lofs[threadIdx.x] += t;
        __syncthreads();
    }
    int excl = lofs[threadIdx.x] - v;
    int n = (b << B2_SHIFT) + threadIdx.x;
    if (n < N_NODES) row_start[n] = beg + excl;
    lcnt[threadIdx.x] = excl;            // reuse as cursor
    __syncthreads();
    for (int i = beg + threadIdx.x; i < end; i += 512) {
        int p = pairs[i];
        int idx = atomicAdd(&lcnt[p & (BUCK_N - 1)], 1);
        sorted_src[beg + idx] = p >> B2_SHIFT;
    }
}

// ============ agg1: wave per node, lane = dim (proven) ============
__global__ __launch_bounds__(256) void k_agg1(const int* __restrict__ row_start,
                                              const int* __restrict__ sorted_src,
                                              const float* __restrict__ x,
                                              float* __restrict__ agg1)
{
    int node = blockIdx.x * 4 + (threadIdx.x >> 6);
    if (node >= N_NODES) return;
    int d = threadIdx.x & 63;
    int beg = row_start[node], end = row_start[node + 1];
    float a0 = 0.0f, a1 = 0.0f;
    int idx = beg;
    for (; idx + 2 <= end; idx += 2) {
        int s0 = sorted_src[idx];
        int s1 = sorted_src[idx + 1];
        a0 += x[(size_t)s0 * 64 + d];
        a1 += x[(size_t)s1 * 64 + d];
    }
    if (idx < end) a0 += x[(size_t)sorted_src[idx] * 64 + d];
    agg1[(size_t)node * 64 + d] = a0 + a1;
}

// ============ node transform: 4 threads/node, conflict-free LDS (proven) ====
#define W2S 36
__global__ __launch_bounds__(256, 3) void k_node(
    const float* __restrict__ x, const float* __restrict__ agg1,
    const int* __restrict__ row_start,
    const float* __restrict__ W1l, const float* __restrict__ b1l,
    const float* __restrict__ W1r, const float* __restrict__ W2l,
    const float* __restrict__ W2r,
    float* __restrict__ t2, float* __restrict__ t3)
{
    __shared__ float sW1l[64 * 64];
    __shared__ float sW1r[64 * 64];
    __shared__ float sW2l[64 * W2S];
    __shared__ float sW2r[64 * W2S];
    {
        float4* d1 = (float4*)sW1l; const float4* g1 = (const float4*)W1l;
        float4* d2 = (float4*)sW1r; const float4* g2 = (const float4*)W1r;
        for (int i = threadIdx.x; i < 1024; i += 256) { d1[i] = g1[i]; d2[i] = g2[i]; }
        const float4* g3 = (const float4*)W2l;
        const float4* g4 = (const float4*)W2r;
        for (int i = threadIdx.x; i < 512; i += 256) {
            int j = i >> 3, q = i & 7;
            *(float4*)(sW2l + j * W2S + q * 4) = g3[i];
            *(float4*)(sW2r + j * W2S + q * 4) = g4[i];
        }
    }
    __syncthreads();

    int t = blockIdx.x * 256 + threadIdx.x;
    int n = t >> 2;
    if (n >= N_NODES) return;
    int jg = t & 3;          // owns j = 16q + 4jg + e (q,e in 0..3)
    float degf = (float)(row_start[n + 1] - row_start[n]);
    float inv = 1.0f / fmaxf(degf, 1.0f);

    float acc[16];
    {
        const float4* bv = (const float4*)b1l;
#pragma unroll
        for (int q = 0; q < 4; q++) {
            float4 b4 = bv[4 * q + jg];
            acc[4*q+0] = b4.x; acc[4*q+1] = b4.y;
            acc[4*q+2] = b4.z; acc[4*q+3] = b4.w;
        }
    }

    const float4* av = (const float4*)(agg1 + (size_t)n * 64);
    const float4* xv = (const float4*)(x + (size_t)n * 64);
    for (int kk = 0; kk < 16; kk++) {
        float4 a4 = av[kk];
        float4 x4 = xv[kk];
        float as[4] = {a4.x * inv, a4.y * inv, a4.z * inv, a4.w * inv};
        float xs[4] = {x4.x, x4.y, x4.z, x4.w};
#pragma unroll
        for (int u = 0; u < 4; u++) {
            int k = kk * 4 + u;
            const float4* wlr = (const float4*)(sW1l + k * 64);
            const float4* wrr = (const float4*)(sW1r + k * 64);
#pragma unroll
            for (int q = 0; q < 4; q++) {
                float4 l4 = wlr[4 * q + jg], r4 = wrr[4 * q + jg];
                acc[4*q+0] += as[u] * l4.x + xs[u] * r4.x;
                acc[4*q+1] += as[u] * l4.y + xs[u] * r4.y;
                acc[4*q+2] += as[u] * l4.z + xs[u] * r4.z;
                acc[4*q+3] += as[u] * l4.w + xs[u] * r4.w;
            }
        }
    }

    float o2[32], o3[32];
#pragma unroll
    for (int o = 0; o < 32; o++) { o2[o] = 0.0f; o3[o] = 0.0f; }
#pragma unroll
    for (int q = 0; q < 4; q++) {
#pragma unroll
        for (int e = 0; e < 4; e++) {
            float hj = fmaxf(acc[4*q+e], 0.0f);
            int j = 16 * q + 4 * jg + e;
            const float4* w2 = (const float4*)(sW2l + j * W2S);
            const float4* w3 = (const float4*)(sW2r + j * W2S);
#pragma unroll
            for (int qq = 0; qq < 8; qq++) {
                float4 a = w2[qq], b = w3[qq];
                o2[4*qq+0] += hj * a.x;  o3[4*qq+0] += hj * b.x;
                o2[4*qq+1] += hj * a.y;  o3[4*qq+1] += hj * b.y;
                o2[4*qq+2] += hj * a.z;  o3[4*qq+2] += hj * b.z;
                o2[4*qq+3] += hj * a.w;  o3[4*qq+3] += hj * b.w;
            }
        }
    }
#pragma unroll
    for (int o = 0; o < 32; o++) {
        o2[o] += __shfl_xor(o2[o], 1);
        o2[o] += __shfl_xor(o2[o], 2);
        o3[o] += __shfl_xor(o3[o], 1);
        o3[o] += __shfl_xor(o3[o], 2);
    }
    float4* t2v = (float4*)(t2 + (size_t)n * 32 + jg * 8);
    float4* t3v = (float4*)(t3 + (size_t)n * 32 + jg * 8);
    if (jg == 0) {
        t2v[0] = make_float4(o2[0], o2[1], o2[2], o2[3]);
        t2v[1] = make_float4(o2[4], o2[5], o2[6], o2[7]);
        t3v[0] = make_float4(o3[0], o3[1], o3[2], o3[3]);
        t3v[1] = make_float4(o3[4], o3[5], o3[6], o3[7]);
    } else if (jg == 1) {
        t2v[0] = make_float4(o2[8], o2[9], o2[10], o2[11]);
        t2v[1] = make_float4(o2[12], o2[13], o2[14], o2[15]);
        t3v[0] = make_float4(o3[8], o3[9], o3[10], o3[11]);
        t3v[1] = make_float4(o3[12], o3[13], o3[14], o3[15]);
    } else if (jg == 2) {
        t2v[0] = make_float4(o2[16], o2[17], o2[18], o2[19]);
        t2v[1] = make_float4(o2[20], o2[21], o2[22], o2[23]);
        t3v[0] = make_float4(o3[16], o3[17], o3[18], o3[19]);
        t3v[1] = make_float4(o3[20], o3[21], o3[22], o3[23]);
    } else {
        t2v[0] = make_float4(o2[24], o2[25], o2[26], o2[27]);
        t2v[1] = make_float4(o2[28], o2[29], o2[30], o2[31]);
        t3v[0] = make_float4(o3[24], o3[25], o3[26], o3[27]);
        t3v[1] = make_float4(o3[28], o3[29], o3[30], o3[31]);
    }
}

// ============ fused agg2 + output (proven) ============
__global__ __launch_bounds__(256) void k_agg2out(
    const int* __restrict__ row_start, const int* __restrict__ sorted_src,
    const float* __restrict__ t2, const float* __restrict__ t3,
    const float* __restrict__ b2l, float* __restrict__ out)
{
    int node = blockIdx.x * 8 + (threadIdx.x >> 5);
    if (node >= N_NODES) return;
    int d = threadIdx.x & 31;
    int beg = row_start[node], end = row_start[node + 1];
    float a0 = 0.0f, a1 = 0.0f;
    int idx = beg;
    for (; idx + 2 <= end; idx += 2) {
        int s0 = sorted_src[idx];
        int s1 = sorted_src[idx + 1];
        a0 += t2[(size_t)s0 * 32 + d];
        a1 += t2[(size_t)s1 * 32 + d];
    }
    if (idx < end) a0 += t2[(size_t)sorted_src[idx] * 32 + d];
    float deg = (float)(end - beg);
    float inv = 1.0f / fmaxf(deg, 1.0f);
    out[(size_t)node * 32 + d] = (a0 + a1) * inv + t3[(size_t)node * 32 + d] + b2l[d];
}

extern "C" void kernel_launch(void* const* d_in, const int* in_sizes, int n_in,
                              void* d_out, int out_size, void* d_ws, size_t ws_size,
                              hipStream_t stream) {
    const float* x   = (const float*)d_in[0];
    const int*   ei  = (const int*)d_in[1];
    const float* W1l = (const float*)d_in[2];
    const float* b1l = (const float*)d_in[3];
    const float* W1r = (const float*)d_in[4];
    const float* W2l = (const float*)d_in[5];
    const float* b2l = (const float*)d_in[6];
    const float* W2r = (const float*)d_in[7];
    float* out = (float*)d_out;

    const size_t N = N_NODES, E = N_EDGES;
    int* wsi = (int*)d_ws;
    int* bcnt       = wsi;                       // NB2  (zeroed)
    int* bbase      = wsi + NB2;                 // NB2+1
    int* bcur       = wsi + 2 * NB2 + 1;         // NB2
    int* row_start  = wsi + 3 * NB2 + 1;         // N+1
    int* pairs      = wsi + 3 * NB2 + 2 + N;     // E
    int* sorted_src = wsi + 3 * NB2 + 2 + N + E; // E
    float* wsf = (float*)(sorted_src + E);
    float* agg1 = wsf;                           // 64N
    float* t2   = wsf + 64 * N;                  // 32N
    float* t3   = wsf + 96 * N;                  // 32N
    // total ~= (3*NB2+2+N+2E)*4 + 128N*4 ~= 65 MB

    hipMemsetAsync(bcnt, 0, NB2 * sizeof(int), stream);
    k_hist <<<HIST_BLOCKS, 256, 0, stream>>>(ei, bcnt);
    k_bscan<<<1, 256, 0, stream>>>(bcnt, bbase, bcur, row_start);
    k_pairs<<<PAIR_BLOCKS, 256, 0, stream>>>(ei, bcur, pairs);
    k_sortb<<<NB2, 512, 0, stream>>>(bbase, pairs, sorted_src, row_start);

    k_agg1   <<<(int)(N / 4), 256, 0, stream>>>(row_start, sorted_src, x, agg1);
    k_node   <<<(int)((N * 4 + 255) / 256), 256, 0, stream>>>(x, agg1, row_start,
                                                W1l, b1l, W1r, W2l, W2r, t2, t3);
    k_agg2out<<<(int)(N / 8), 256, 0, stream>>>(row_start, sorted_src, t2, t3, b2l, out);
}

// Round 11
// 343.629 us; speedup vs baseline: 4.0679x; 1.0582x over previous
//
#include <hip/hip_runtime.h>

#define N_NODES 100000
#define N_EDGES 1600000
#define B2_SHIFT 9
#define BUCK_N (1 << B2_SHIFT)                   // 512 nodes per bucket
#define NB2 ((N_NODES + BUCK_N - 1) >> B2_SHIFT) // 196 buckets
#define HIST_EPB 8192
#define HIST_BLOCKS ((N_EDGES + HIST_EPB - 1) / HIST_EPB)   // 196
#define PAIR_EPB 2048
#define PAIR_BLOCKS ((N_EDGES + PAIR_EPB - 1) / PAIR_EPB)   // 782

// ---- bf16 pack/unpack helpers (RNE) ----
__device__ __forceinline__ unsigned pack2(float a, float b) {
    unsigned ua = __float_as_uint(a), ub = __float_as_uint(b);
    ua = (ua + 0x7FFFu + ((ua >> 16) & 1u)) >> 16;
    ub = (ub + 0x7FFFu + ((ub >> 16) & 1u)) >> 16;
    return ua | (ub << 16);
}
__device__ __forceinline__ float lo16(unsigned u) { return __uint_as_float(u << 16); }
__device__ __forceinline__ float hi16(unsigned u) { return __uint_as_float(u & 0xFFFF0000u); }

// ============ cast x -> packed bf16 (dims pair-packed) ============
__global__ __launch_bounds__(256) void k_cast(const float* __restrict__ x,
                                              unsigned* __restrict__ xh)
{
    int i = blockIdx.x * 256 + threadIdx.x;   // over 32N uints
    if (i < N_NODES * 32) {
        float2 v = ((const float2*)x)[i];
        xh[i] = pack2(v.x, v.y);
    }
}

// ============ bucket histogram: chunked, few flush atomics ============
__global__ __launch_bounds__(256) void k_hist(const int* __restrict__ ei,
                                              int* __restrict__ bcnt)
{
    __shared__ int lh[NB2];
    for (int i = threadIdx.x; i < NB2; i += 256) lh[i] = 0;
    __syncthreads();
    int base = blockIdx.x * HIST_EPB;
#pragma unroll 4
    for (int t = 0; t < HIST_EPB / 256; t++) {
        int e = base + t * 256 + threadIdx.x;
        if (e < N_EDGES) atomicAdd(&lh[ei[N_EDGES + e] >> B2_SHIFT], 1);
    }
    __syncthreads();
    for (int i = threadIdx.x; i < NB2; i += 256)
        if (lh[i]) atomicAdd(&bcnt[i], lh[i]);
}

// ============ scan bucket counts (single block) ============
__global__ __launch_bounds__(256) void k_bscan(const int* __restrict__ bcnt,
                                               int* __restrict__ bbase,
                                               int* __restrict__ bcur,
                                               int* __restrict__ row_start)
{
    __shared__ int s[256];
    int v = (threadIdx.x < NB2) ? bcnt[threadIdx.x] : 0;
    s[threadIdx.x] = v;
    __syncthreads();
    for (int off = 1; off < 256; off <<= 1) {
        int t = (threadIdx.x >= off) ? s[threadIdx.x - off] : 0;
        __syncthreads();
        s[threadIdx.x] += t;
        __syncthreads();
    }
    if (threadIdx.x < NB2) {
        int ex = s[threadIdx.x] - v;
        bbase[threadIdx.x] = ex;
        bcur[threadIdx.x] = ex;
    }
    if (threadIdx.x == 0) { bbase[NB2] = N_EDGES; row_start[N_NODES] = N_EDGES; }
}

// ============ bucket edges: pairs[slot] = (src<<9) | (dst & 511) ============
__global__ __launch_bounds__(256) void k_pairs(const int* __restrict__ ei,
                                               int* __restrict__ bcur,
                                               int* __restrict__ pairs)
{
    __shared__ int lh[NB2];
    __shared__ int lbase[NB2];
    for (int i = threadIdx.x; i < NB2; i += 256) lh[i] = 0;
    __syncthreads();
    int base = blockIdx.x * PAIR_EPB;
    int myb[8], myr[8], myp[8];
#pragma unroll
    for (int t = 0; t < 8; t++) {
        int e = base + t * 256 + threadIdx.x;
        myb[t] = -1;
        if (e < N_EDGES) {
            int dst = ei[N_EDGES + e];
            int b = dst >> B2_SHIFT;
            myb[t] = b;
            myr[t] = atomicAdd(&lh[b], 1);
            myp[t] = (ei[e] << B2_SHIFT) | (dst & (BUCK_N - 1));
        }
    }
    __syncthreads();
    for (int i = threadIdx.x; i < NB2; i += 256)
        lbase[i] = lh[i] ? atomicAdd(&bcur[i], lh[i]) : 0;
    __syncthreads();
#pragma unroll
    for (int t = 0; t < 8; t++)
        if (myb[t] >= 0) pairs[lbase[myb[t]] + myr[t]] = myp[t];
}

// ============ per-bucket CSR finalize ============
__global__ __launch_bounds__(512) void k_sortb(const int* __restrict__ bbase,
                                               const int* __restrict__ pairs,
                                               int* __restrict__ sorted_src,
                                               int* __restrict__ row_start)
{
    __shared__ int lcnt[BUCK_N];
    __shared__ int lofs[BUCK_N];
    int b = blockIdx.x;
    int beg = bbase[b], end = bbase[b + 1];
    lcnt[threadIdx.x] = 0;
    __syncthreads();
    for (int i = beg + threadIdx.x; i < end; i += 512)
        atomicAdd(&lcnt[pairs[i] & (BUCK_N - 1)], 1);
    __syncthreads();
    int v = lcnt[threadIdx.x];
    lofs[threadIdx.x] = v;
    __syncthreads();
    for (int off = 1; off < BUCK_N; off <<= 1) {
        int t = (threadIdx.x >= off) ? lofs[threadIdx.x - off] : 0;
        __syncthreads();
        lofs[threadIdx.x] += t;
        __syncthreads();
    }
    int excl = lofs[threadIdx.x] - v;
    int n = (b << B2_SHIFT) + threadIdx.x;
    if (n < N_NODES) row_start[n] = beg + excl;
    lcnt[threadIdx.x] = excl;
    __syncthreads();
    for (int i = beg + threadIdx.x; i < end; i += 512) {
        int p = pairs[i];
        int idx = atomicAdd(&lcnt[p & (BUCK_N - 1)], 1);
        sorted_src[beg + idx] = p >> B2_SHIFT;
    }
}

// ============ agg1: 32 lanes/node, lane = dim-pair, bf16 gather ============
__global__ __launch_bounds__(256) void k_agg1(const int* __restrict__ row_start,
                                              const int* __restrict__ sorted_src,
                                              const unsigned* __restrict__ xh,
                                              float* __restrict__ agg1)
{
    int node = blockIdx.x * 8 + (threadIdx.x >> 5);
    if (node >= N_NODES) return;
    int d2 = threadIdx.x & 31;       // dims 2*d2, 2*d2+1
    int beg = row_start[node], end = row_start[node + 1];
    float a0 = 0.f, a1 = 0.f, b0 = 0.f, b1 = 0.f;
    int idx = beg;
    for (; idx + 4 <= end; idx += 4) {
        int s0 = sorted_src[idx], s1 = sorted_src[idx + 1];
        int s2 = sorted_src[idx + 2], s3 = sorted_src[idx + 3];
        unsigned p0 = xh[(size_t)s0 * 32 + d2];
        unsigned p1 = xh[(size_t)s1 * 32 + d2];
        unsigned p2 = xh[(size_t)s2 * 32 + d2];
        unsigned p3 = xh[(size_t)s3 * 32 + d2];
        a0 += lo16(p0) + lo16(p1);  a1 += hi16(p0) + hi16(p1);
        b0 += lo16(p2) + lo16(p3);  b1 += hi16(p2) + hi16(p3);
    }
    for (; idx < end; idx++) {
        unsigned p = xh[(size_t)sorted_src[idx] * 32 + d2];
        a0 += lo16(p);  a1 += hi16(p);
    }
    ((float2*)(agg1 + (size_t)node * 64))[d2] = make_float2(a0 + b0, a1 + b1);
}

// ============ node transform: 4 threads/node, conflict-free LDS ============
#define W2S 36
__global__ __launch_bounds__(256, 3) void k_node(
    const float* __restrict__ x, const float* __restrict__ agg1,
    const int* __restrict__ row_start,
    const float* __restrict__ W1l, const float* __restrict__ b1l,
    const float* __restrict__ W1r, const float* __restrict__ W2l,
    const float* __restrict__ W2r,
    unsigned* __restrict__ t2h, float* __restrict__ t3)
{
    __shared__ float sW1l[64 * 64];
    __shared__ float sW1r[64 * 64];
    __shared__ float sW2l[64 * W2S];
    __shared__ float sW2r[64 * W2S];
    {
        float4* d1 = (float4*)sW1l; const float4* g1 = (const float4*)W1l;
        float4* d2 = (float4*)sW1r; const float4* g2 = (const float4*)W1r;
        for (int i = threadIdx.x; i < 1024; i += 256) { d1[i] = g1[i]; d2[i] = g2[i]; }
        const float4* g3 = (const float4*)W2l;
        const float4* g4 = (const float4*)W2r;
        for (int i = threadIdx.x; i < 512; i += 256) {
            int j = i >> 3, q = i & 7;
            *(float4*)(sW2l + j * W2S + q * 4) = g3[i];
            *(float4*)(sW2r + j * W2S + q * 4) = g4[i];
        }
    }
    __syncthreads();

    int t = blockIdx.x * 256 + threadIdx.x;
    int n = t >> 2;
    if (n >= N_NODES) return;
    int jg = t & 3;          // owns j = 16q + 4jg + e (q,e in 0..3)
    float degf = (float)(row_start[n + 1] - row_start[n]);
    float inv = 1.0f / fmaxf(degf, 1.0f);

    float acc[16];
    {
        const float4* bv = (const float4*)b1l;
#pragma unroll
        for (int q = 0; q < 4; q++) {
            float4 b4 = bv[4 * q + jg];
            acc[4*q+0] = b4.x; acc[4*q+1] = b4.y;
            acc[4*q+2] = b4.z; acc[4*q+3] = b4.w;
        }
    }

    const float4* av = (const float4*)(agg1 + (size_t)n * 64);
    const float4* xv = (const float4*)(x + (size_t)n * 64);
    for (int kk = 0; kk < 16; kk++) {
        float4 a4 = av[kk];
        float4 x4 = xv[kk];
        float as[4] = {a4.x * inv, a4.y * inv, a4.z * inv, a4.w * inv};
        float xs[4] = {x4.x, x4.y, x4.z, x4.w};
#pragma unroll
        for (int u = 0; u < 4; u++) {
            int k = kk * 4 + u;
            const float4* wlr = (const float4*)(sW1l + k * 64);
            const float4* wrr = (const float4*)(sW1r + k * 64);
#pragma unroll
            for (int q = 0; q < 4; q++) {
                float4 l4 = wlr[4 * q + jg], r4 = wrr[4 * q + jg];
                acc[4*q+0] += as[u] * l4.x + xs[u] * r4.x;
                acc[4*q+1] += as[u] * l4.y + xs[u] * r4.y;
                acc[4*q+2] += as[u] * l4.z + xs[u] * r4.z;
                acc[4*q+3] += as[u] * l4.w + xs[u] * r4.w;
            }
        }
    }

    float o2[32], o3[32];
#pragma unroll
    for (int o = 0; o < 32; o++) { o2[o] = 0.0f; o3[o] = 0.0f; }
#pragma unroll
    for (int q = 0; q < 4; q++) {
#pragma unroll
        for (int e = 0; e < 4; e++) {
            float hj = fmaxf(acc[4*q+e], 0.0f);
            int j = 16 * q + 4 * jg + e;
            const float4* w2 = (const float4*)(sW2l + j * W2S);
            const float4* w3 = (const float4*)(sW2r + j * W2S);
#pragma unroll
            for (int qq = 0; qq < 8; qq++) {
                float4 a = w2[qq], b = w3[qq];
                o2[4*qq+0] += hj * a.x;  o3[4*qq+0] += hj * b.x;
                o2[4*qq+1] += hj * a.y;  o3[4*qq+1] += hj * b.y;
                o2[4*qq+2] += hj * a.z;  o3[4*qq+2] += hj * b.z;
                o2[4*qq+3] += hj * a.w;  o3[4*qq+3] += hj * b.w;
            }
        }
    }
#pragma unroll
    for (int o = 0; o < 32; o++) {
        o2[o] += __shfl_xor(o2[o], 1);
        o2[o] += __shfl_xor(o2[o], 2);
        o3[o] += __shfl_xor(o3[o], 1);
        o3[o] += __shfl_xor(o3[o], 2);
    }
    unsigned* t2p = t2h + (size_t)n * 16 + jg * 4;
    float4* t3v = (float4*)(t3 + (size_t)n * 32 + jg * 8);
    if (jg == 0) {
        *(uint4*)t2p = make_uint4(pack2(o2[0], o2[1]), pack2(o2[2], o2[3]),
                                  pack2(o2[4], o2[5]), pack2(o2[6], o2[7]));
        t3v[0] = make_float4(o3[0], o3[1], o3[2], o3[3]);
        t3v[1] = make_float4(o3[4], o3[5], o3[6], o3[7]);
    } else if (jg == 1) {
        *(uint4*)t2p = make_uint4(pack2(o2[8], o2[9]), pack2(o2[10], o2[11]),
                                  pack2(o2[12], o2[13]), pack2(o2[14], o2[15]));
        t3v[0] = make_float4(o3[8], o3[9], o3[10], o3[11]);
        t3v[1] = make_float4(o3[12], o3[13], o3[14], o3[15]);
    } else if (jg == 2) {
        *(uint4*)t2p = make_uint4(pack2(o2[16], o2[17]), pack2(o2[18], o2[19]),
                                  pack2(o2[20], o2[21]), pack2(o2[22], o2[23]));
        t3v[0] = make_float4(o3[16], o3[17], o3[18], o3[19]);
        t3v[1] = make_float4(o3[20], o3[21], o3[22], o3[23]);
    } else {
        *(uint4*)t2p = make_uint4(pack2(o2[24], o2[25]), pack2(o2[26], o2[27]),
                                  pack2(o2[28], o2[29]), pack2(o2[30], o2[31]));
        t3v[0] = make_float4(o3[24], o3[25], o3[26], o3[27]);
        t3v[1] = make_float4(o3[28], o3[29], o3[30], o3[31]);
    }
}

// ============ agg2 + output: 16 lanes/node, bf16 gather (64 B/edge) ========
__global__ __launch_bounds__(256) void k_agg2out(
    const int* __restrict__ row_start, const int* __restrict__ sorted_src,
    const unsigned* __restrict__ t2h, const float* __restrict__ t3,
    const float* __restrict__ b2l, float* __restrict__ out)
{
    int node = blockIdx.x * 16 + (threadIdx.x >> 4);
    if (node >= N_NODES) return;
    int d2 = threadIdx.x & 15;       // dims 2*d2, 2*d2+1
    int beg = row_start[node], end = row_start[node + 1];
    float a0 = 0.f, a1 = 0.f, b0 = 0.f, b1 = 0.f;
    int idx = beg;
    for (; idx + 4 <= end; idx += 4) {
        int s0 = sorted_src[idx], s1 = sorted_src[idx + 1];
        int s2 = sorted_src[idx + 2], s3 = sorted_src[idx + 3];
        unsigned p0 = t2h[(size_t)s0 * 16 + d2];
        unsigned p1 = t2h[(size_t)s1 * 16 + d2];
        unsigned p2 = t2h[(size_t)s2 * 16 + d2];
        unsigned p3 = t2h[(size_t)s3 * 16 + d2];
        a0 += lo16(p0) + lo16(p1);  a1 += hi16(p0) + hi16(p1);
        b0 += lo16(p2) + lo16(p3);  b1 += hi16(p2) + hi16(p3);
    }
    for (; idx < end; idx++) {
        unsigned p = t2h[(size_t)sorted_src[idx] * 16 + d2];
        a0 += lo16(p);  a1 += hi16(p);
    }
    float inv = 1.0f / fmaxf((float)(end - beg), 1.0f);
    float2 tv = ((const float2*)(t3 + (size_t)node * 32))[d2];
    float2 bv = ((const float2*)b2l)[d2];
    ((float2*)(out + (size_t)node * 32))[d2] =
        make_float2((a0 + b0) * inv + tv.x + bv.x,
                    (a1 + b1) * inv + tv.y + bv.y);
}

extern "C" void kernel_launch(void* const* d_in, const int* in_sizes, int n_in,
                              void* d_out, int out_size, void* d_ws, size_t ws_size,
                              hipStream_t stream) {
    const float* x   = (const float*)d_in[0];
    const int*   ei  = (const int*)d_in[1];
    const float* W1l = (const float*)d_in[2];
    const float* b1l = (const float*)d_in[3];
    const float* W1r = (const float*)d_in[4];
    const float* W2l = (const float*)d_in[5];
    const float* b2l = (const float*)d_in[6];
    const float* W2r = (const float*)d_in[7];
    float* out = (float*)d_out;

    const size_t N = N_NODES, E = N_EDGES;
    int* wsi = (int*)d_ws;
    int* bcnt       = wsi;                       // NB2  (zeroed)
    int* bbase      = wsi + NB2;                 // NB2+1
    int* bcur       = wsi + 2 * NB2 + 1;         // NB2
    int* row_start  = wsi + 3 * NB2 + 1;         // N+1
    int* pairs      = wsi + 3 * NB2 + 2 + N;     // E
    int* sorted_src = wsi + 3 * NB2 + 2 + N + E; // E
    unsigned* xh    = (unsigned*)(sorted_src + E);  // 32N
    unsigned* t2h   = xh + 32 * N;                  // 16N
    float* wsf = (float*)(t2h + 16 * N);
    float* agg1 = wsf;                           // 64N
    float* t3   = wsf + 64 * N;                  // 32N
    // total ~= (N + 2E + 48N + 96N)*4 + small ~= 71 MB

    hipMemsetAsync(bcnt, 0, NB2 * sizeof(int), stream);
    k_cast <<<(int)((N * 32 + 255) / 256), 256, 0, stream>>>(x, xh);
    k_hist <<<HIST_BLOCKS, 256, 0, stream>>>(ei, bcnt);
    k_bscan<<<1, 256, 0, stream>>>(bcnt, bbase, bcur, row_start);
    k_pairs<<<PAIR_BLOCKS, 256, 0, stream>>>(ei, bcur, pairs);
    k_sortb<<<NB2, 512, 0, stream>>>(bbase, pairs, sorted_src, row_start);

    k_agg1   <<<(int)((N + 7) / 8), 256, 0, stream>>>(row_start, sorted_src, xh, agg1);
    k_node   <<<(int)((N * 4 + 255) / 256), 256, 0, stream>>>(x, agg1, row_start,
                                                W1l, b1l, W1r, W2l, W2r, t2h, t3);
    k_agg2out<<<(int)((N + 15) / 16), 256, 0, stream>>>(row_start, sorted_src,
                                                t2h, t3, b2l, out);
}

// Round 12
// 262.739 us; speedup vs baseline: 5.3203x; 1.3079x over previous
//
#include <hip/hip_runtime.h>

#define N_NODES 100000
#define N_EDGES 1600000
#define B2_SHIFT 9
#define BUCK_N (1 << B2_SHIFT)                   // 512 nodes per bucket
#define NB2 ((N_NODES + BUCK_N - 1) >> B2_SHIFT) // 196 buckets
#define BCAP 9216                                // padded bucket capacity (avg 8163)
#define PAIR_EPB 2048
#define PAIR_BLOCKS ((N_EDGES + PAIR_EPB - 1) / PAIR_EPB)   // 782

// ---- bf16 pack/unpack helpers (RNE) ----
__device__ __forceinline__ unsigned pack2(float a, float b) {
    unsigned ua = __float_as_uint(a), ub = __float_as_uint(b);
    ua = (ua + 0x7FFFu + ((ua >> 16) & 1u)) >> 16;
    ub = (ub + 0x7FFFu + ((ub >> 16) & 1u)) >> 16;
    return ua | (ub << 16);
}
__device__ __forceinline__ float lo16(unsigned u) { return __uint_as_float(u << 16); }
__device__ __forceinline__ float hi16(unsigned u) { return __uint_as_float(u & 0xFFFF0000u); }

// ============ cast x -> packed bf16 (dims pair-packed) ============
__global__ __launch_bounds__(256) void k_cast(const float* __restrict__ x,
                                              unsigned* __restrict__ xh)
{
    int i = blockIdx.x * 256 + threadIdx.x;   // over 32N uints
    if (i < N_NODES * 32) {
        float2 v = ((const float2*)x)[i];
        xh[i] = pack2(v.x, v.y);
    }
}

// ============ init padded-bucket cursors ============
__global__ __launch_bounds__(256) void k_initcur(int* __restrict__ bcur)
{
    if (threadIdx.x < NB2) bcur[threadIdx.x] = threadIdx.x * BCAP;
}

// ============ bucket edges into padded regions: (src<<9)|(dst&511) =========
__global__ __launch_bounds__(256) void k_pairs(const int* __restrict__ ei,
                                               int* __restrict__ bcur,
                                               int* __restrict__ pairs)
{
    __shared__ int lh[NB2];
    __shared__ int lbase[NB2];
    for (int i = threadIdx.x; i < NB2; i += 256) lh[i] = 0;
    __syncthreads();
    int base = blockIdx.x * PAIR_EPB;
    int myb[8], myr[8], myp[8];
#pragma unroll
    for (int t = 0; t < 8; t++) {
        int e = base + t * 256 + threadIdx.x;
        myb[t] = -1;
        if (e < N_EDGES) {
            int dst = ei[N_EDGES + e];
            int b = dst >> B2_SHIFT;
            myb[t] = b;
            myr[t] = atomicAdd(&lh[b], 1);
            myp[t] = (ei[e] << B2_SHIFT) | (dst & (BUCK_N - 1));
        }
    }
    __syncthreads();
    for (int i = threadIdx.x; i < NB2; i += 256)
        lbase[i] = lh[i] ? atomicAdd(&bcur[i], lh[i]) : 0;
    __syncthreads();
#pragma unroll
    for (int t = 0; t < 8; t++) {
        if (myb[t] >= 0) {
            int slot = lbase[myb[t]] + myr[t];
            if (slot < (myb[t] + 1) * BCAP)   // defensive (never expected)
                pairs[slot] = myp[t];
        }
    }
}

// ============ per-bucket CSR finalize: hist+scan+scatter; emits rs/re =======
__global__ __launch_bounds__(512) void k_sortb(const int* __restrict__ bcur,
                                               const int* __restrict__ pairs,
                                               int* __restrict__ sorted_src,
                                               int* __restrict__ rs,
                                               int* __restrict__ re)
{
    __shared__ int lcnt[BUCK_N];
    __shared__ int lofs[BUCK_N];
    int b = blockIdx.x;
    int beg = b * BCAP, end = bcur[b];
    lcnt[threadIdx.x] = 0;
    __syncthreads();
    for (int i = beg + threadIdx.x; i < end; i += 512)
        atomicAdd(&lcnt[pairs[i] & (BUCK_N - 1)], 1);
    __syncthreads();
    int v = lcnt[threadIdx.x];
    lofs[threadIdx.x] = v;
    __syncthreads();
    for (int off = 1; off < BUCK_N; off <<= 1) {
        int t = (threadIdx.x >= off) ? lofs[threadIdx.x - off] : 0;
        __syncthreads();
        lofs[threadIdx.x] += t;
        __syncthreads();
    }
    int excl = lofs[threadIdx.x] - v;
    int n = (b << B2_SHIFT) + threadIdx.x;
    if (n < N_NODES) { rs[n] = beg + excl; re[n] = beg + excl + v; }
    lcnt[threadIdx.x] = excl;
    __syncthreads();
    for (int i = beg + threadIdx.x; i < end; i += 512) {
        int p = pairs[i];
        int idx = atomicAdd(&lcnt[p & (BUCK_N - 1)], 1);
        sorted_src[beg + idx] = p >> B2_SHIFT;
    }
}

// ============ agg1: 32 lanes/node, lane = dim-pair, bf16 gather ============
__global__ __launch_bounds__(256) void k_agg1(const int* __restrict__ rs,
                                              const int* __restrict__ re,
                                              const int* __restrict__ sorted_src,
                                              const unsigned* __restrict__ xh,
                                              float* __restrict__ agg1)
{
    int node = blockIdx.x * 8 + (threadIdx.x >> 5);
    if (node >= N_NODES) return;
    int d2 = threadIdx.x & 31;       // dims 2*d2, 2*d2+1
    int beg = rs[node], end = re[node];
    float a0 = 0.f, a1 = 0.f, b0 = 0.f, b1 = 0.f;
    int idx = beg;
    for (; idx + 4 <= end; idx += 4) {
        int s0 = sorted_src[idx], s1 = sorted_src[idx + 1];
        int s2 = sorted_src[idx + 2], s3 = sorted_src[idx + 3];
        unsigned p0 = xh[(size_t)s0 * 32 + d2];
        unsigned p1 = xh[(size_t)s1 * 32 + d2];
        unsigned p2 = xh[(size_t)s2 * 32 + d2];
        unsigned p3 = xh[(size_t)s3 * 32 + d2];
        a0 += lo16(p0) + lo16(p1);  a1 += hi16(p0) + hi16(p1);
        b0 += lo16(p2) + lo16(p3);  b1 += hi16(p2) + hi16(p3);
    }
    for (; idx < end; idx++) {
        unsigned p = xh[(size_t)sorted_src[idx] * 32 + d2];
        a0 += lo16(p);  a1 += hi16(p);
    }
    ((float2*)(agg1 + (size_t)node * 64))[d2] = make_float2(a0 + b0, a1 + b1);
}

// ============ node transform: 4 threads/node, low-register layer 2 =========
// Layer 1: thread jg owns h[j], j = 16q+4jg+e (acc[16]).
// Layer 2: thread jg owns outputs o in [jg*8,jg*8+8) of BOTH t2 and t3;
// h values stream in via __shfl_xor across the quad -> only 16 accumulators.
#define W2S 36
__global__ __launch_bounds__(256, 3) void k_node(
    const float* __restrict__ x, const float* __restrict__ agg1,
    const int* __restrict__ rs, const int* __restrict__ re,
    const float* __restrict__ W1l, const float* __restrict__ b1l,
    const float* __restrict__ W1r, const float* __restrict__ W2l,
    const float* __restrict__ W2r,
    unsigned* __restrict__ t2h, float* __restrict__ t3)
{
    __shared__ float sW1l[64 * 64];
    __shared__ float sW1r[64 * 64];
    __shared__ float sW2l[64 * W2S];
    __shared__ float sW2r[64 * W2S];
    {
        float4* d1 = (float4*)sW1l; const float4* g1 = (const float4*)W1l;
        float4* d2 = (float4*)sW1r; const float4* g2 = (const float4*)W1r;
        for (int i = threadIdx.x; i < 1024; i += 256) { d1[i] = g1[i]; d2[i] = g2[i]; }
        const float4* g3 = (const float4*)W2l;
        const float4* g4 = (const float4*)W2r;
        for (int i = threadIdx.x; i < 512; i += 256) {
            int j = i >> 3, q = i & 7;
            *(float4*)(sW2l + j * W2S + q * 4) = g3[i];
            *(float4*)(sW2r + j * W2S + q * 4) = g4[i];
        }
    }
    __syncthreads();

    int t = blockIdx.x * 256 + threadIdx.x;
    int n = t >> 2;
    if (n >= N_NODES) return;
    int jg = t & 3;
    float degf = (float)(re[n] - rs[n]);
    float inv = 1.0f / fmaxf(degf, 1.0f);

    float acc[16];
    {
        const float4* bv = (const float4*)b1l;
#pragma unroll
        for (int q = 0; q < 4; q++) {
            float4 b4 = bv[4 * q + jg];
            acc[4*q+0] = b4.x; acc[4*q+1] = b4.y;
            acc[4*q+2] = b4.z; acc[4*q+3] = b4.w;
        }
    }

    const float4* av = (const float4*)(agg1 + (size_t)n * 64);
    const float4* xv = (const float4*)(x + (size_t)n * 64);
    for (int kk = 0; kk < 16; kk++) {
        float4 a4 = av[kk];
        float4 x4 = xv[kk];
        float as[4] = {a4.x * inv, a4.y * inv, a4.z * inv, a4.w * inv};
        float xs[4] = {x4.x, x4.y, x4.z, x4.w};
#pragma unroll
        for (int u = 0; u < 4; u++) {
            int k = kk * 4 + u;
            const float4* wlr = (const float4*)(sW1l + k * 64);
            const float4* wrr = (const float4*)(sW1r + k * 64);
#pragma unroll
            for (int q = 0; q < 4; q++) {
                float4 l4 = wlr[4 * q + jg], r4 = wrr[4 * q + jg];
                acc[4*q+0] += as[u] * l4.x + xs[u] * r4.x;
                acc[4*q+1] += as[u] * l4.y + xs[u] * r4.y;
                acc[4*q+2] += as[u] * l4.z + xs[u] * r4.z;
                acc[4*q+3] += as[u] * l4.w + xs[u] * r4.w;
            }
        }
    }
    // relu in place: acc now holds h[j] for this thread's 16 j's
#pragma unroll
    for (int jj = 0; jj < 16; jj++) acc[jj] = fmaxf(acc[jj], 0.0f);

    // layer 2: stream h across the quad; 8+8 accumulators only
    float o2[8], o3[8];
#pragma unroll
    for (int o = 0; o < 8; o++) { o2[o] = 0.0f; o3[o] = 0.0f; }
#pragma unroll
    for (int r = 0; r < 4; r++) {
#pragma unroll
        for (int jj = 0; jj < 16; jj++) {
            float hv = (r == 0) ? acc[jj] : __shfl_xor(acc[jj], r);
            int q = jj >> 2, e = jj & 3;
            int j = 16 * q + 4 * (jg ^ r) + e;   // j owned by source lane
            const float4* w2 = (const float4*)(sW2l + j * W2S + jg * 8);
            const float4* w3 = (const float4*)(sW2r + j * W2S + jg * 8);
            float4 a = w2[0], aa = w2[1];
            float4 b = w3[0], bb = w3[1];
            o2[0] += hv * a.x;  o2[1] += hv * a.y;
            o2[2] += hv * a.z;  o2[3] += hv * a.w;
            o2[4] += hv * aa.x; o2[5] += hv * aa.y;
            o2[6] += hv * aa.z; o2[7] += hv * aa.w;
            o3[0] += hv * b.x;  o3[1] += hv * b.y;
            o3[2] += hv * b.z;  o3[3] += hv * b.w;
            o3[4] += hv * bb.x; o3[5] += hv * bb.y;
            o3[6] += hv * bb.z; o3[7] += hv * bb.w;
        }
    }
    // thread jg owns outputs [jg*8, jg*8+8) of t2 and t3
    unsigned* t2p = t2h + (size_t)n * 16 + jg * 4;
    *(uint4*)t2p = make_uint4(pack2(o2[0], o2[1]), pack2(o2[2], o2[3]),
                              pack2(o2[4], o2[5]), pack2(o2[6], o2[7]));
    float4* t3v = (float4*)(t3 + (size_t)n * 32 + jg * 8);
    t3v[0] = make_float4(o3[0], o3[1], o3[2], o3[3]);
    t3v[1] = make_float4(o3[4], o3[5], o3[6], o3[7]);
}

// ============ agg2 + output: 16 lanes/node, bf16 gather (64 B/edge) ========
__global__ __launch_bounds__(256) void k_agg2out(
    const int* __restrict__ rs, const int* __restrict__ re,
    const int* __restrict__ sorted_src,
    const unsigned* __restrict__ t2h, const float* __restrict__ t3,
    const float* __restrict__ b2l, float* __restrict__ out)
{
    int node = blockIdx.x * 16 + (threadIdx.x >> 4);
    if (node >= N_NODES) return;
    int d2 = threadIdx.x & 15;       // dims 2*d2, 2*d2+1
    int beg = rs[node], end = re[node];
    float a0 = 0.f, a1 = 0.f, b0 = 0.f, b1 = 0.f;
    int idx = beg;
    for (; idx + 4 <= end; idx += 4) {
        int s0 = sorted_src[idx], s1 = sorted_src[idx + 1];
        int s2 = sorted_src[idx + 2], s3 = sorted_src[idx + 3];
        unsigned p0 = t2h[(size_t)s0 * 16 + d2];
        unsigned p1 = t2h[(size_t)s1 * 16 + d2];
        unsigned p2 = t2h[(size_t)s2 * 16 + d2];
        unsigned p3 = t2h[(size_t)s3 * 16 + d2];
        a0 += lo16(p0) + lo16(p1);  a1 += hi16(p0) + hi16(p1);
        b0 += lo16(p2) + lo16(p3);  b1 += hi16(p2) + hi16(p3);
    }
    for (; idx < end; idx++) {
        unsigned p = t2h[(size_t)sorted_src[idx] * 16 + d2];
        a0 += lo16(p);  a1 += hi16(p);
    }
    float inv = 1.0f / fmaxf((float)(end - beg), 1.0f);
    float2 tv = ((const float2*)(t3 + (size_t)node * 32))[d2];
    float2 bv = ((const float2*)b2l)[d2];
    ((float2*)(out + (size_t)node * 32))[d2] =
        make_float2((a0 + b0) * inv + tv.x + bv.x,
                    (a1 + b1) * inv + tv.y + bv.y);
}

extern "C" void kernel_launch(void* const* d_in, const int* in_sizes, int n_in,
                              void* d_out, int out_size, void* d_ws, size_t ws_size,
                              hipStream_t stream) {
    const float* x   = (const float*)d_in[0];
    const int*   ei  = (const int*)d_in[1];
    const float* W1l = (const float*)d_in[2];
    const float* b1l = (const float*)d_in[3];
    const float* W1r = (const float*)d_in[4];
    const float* W2l = (const float*)d_in[5];
    const float* b2l = (const float*)d_in[6];
    const float* W2r = (const float*)d_in[7];
    float* out = (float*)d_out;

    const size_t N = N_NODES;
    // All offsets are multiples of 16 ints (64 B) for aligned float4/uint4.
    int* wsi = (int*)d_ws;
    int*      pairs      = wsi;                          // NB2*BCAP = 1806336
    int*      sorted_src = wsi + 1806336;                // NB2*BCAP
    int*      bcur       = wsi + 3612672;                // 256
    int*      rs         = wsi + 3612928;                // N
    int*      re         = wsi + 3712928;                // N
    unsigned* xh         = (unsigned*)(wsi + 3812928);   // 32N
    unsigned* t2h        = (unsigned*)(wsi + 3812928) + 32 * N;  // 16N
    float*    agg1       = (float*)(t2h + 16 * N);       // 64N
    float*    t3         = agg1 + 64 * N;                // 32N
    // total ~= 18.2M ints ~= 73 MB

    k_cast   <<<(int)((N * 32 + 255) / 256), 256, 0, stream>>>(x, xh);
    k_initcur<<<1, 256, 0, stream>>>(bcur);
    k_pairs  <<<PAIR_BLOCKS, 256, 0, stream>>>(ei, bcur, pairs);
    k_sortb  <<<NB2, 512, 0, stream>>>(bcur, pairs, sorted_src, rs, re);

    k_agg1   <<<(int)((N + 7) / 8), 256, 0, stream>>>(rs, re, sorted_src, xh, agg1);
    k_node   <<<(int)((N * 4 + 255) / 256), 256, 0, stream>>>(x, agg1, rs, re,
                                                W1l, b1l, W1r, W2l, W2r, t2h, t3);
    k_agg2out<<<(int)((N + 15) / 16), 256, 0, stream>>>(rs, re, sorted_src,
                                                t2h, t3, b2l, out);
}

// Round 13
// 221.897 us; speedup vs baseline: 6.2996x; 1.1841x over previous
//
#include <hip/hip_runtime.h>

#define N_NODES 100000
#define N_EDGES 1600000
#define B2_SHIFT 9
#define BUCK_N (1 << B2_SHIFT)                   // 512 nodes per bucket
#define NB2 ((N_NODES + BUCK_N - 1) >> B2_SHIFT) // 196 buckets
#define BCAP 9216                                // padded bucket capacity (avg 8163)
#define PAIR_EPB 2048
#define PAIR_BLOCKS ((N_EDGES + PAIR_EPB - 1) / PAIR_EPB)   // 782

typedef __attribute__((ext_vector_type(8))) short bf16x8;
typedef __attribute__((ext_vector_type(4))) float f32x4;

// ---- bf16 pack/unpack helpers (RNE) ----
__device__ __forceinline__ unsigned pack2(float a, float b) {
    unsigned ua = __float_as_uint(a), ub = __float_as_uint(b);
    ua = (ua + 0x7FFFu + ((ua >> 16) & 1u)) >> 16;
    ub = (ub + 0x7FFFu + ((ub >> 16) & 1u)) >> 16;
    return ua | (ub << 16);
}
__device__ __forceinline__ float lo16(unsigned u) { return __uint_as_float(u << 16); }
__device__ __forceinline__ float hi16(unsigned u) { return __uint_as_float(u & 0xFFFF0000u); }

// ============ cast x -> packed bf16 (dims pair-packed) ============
__global__ __launch_bounds__(256) void k_cast(const float* __restrict__ x,
                                              unsigned* __restrict__ xh)
{
    int i = blockIdx.x * 256 + threadIdx.x;   // over 32N uints
    if (i < N_NODES * 32) {
        float2 v = ((const float2*)x)[i];
        xh[i] = pack2(v.x, v.y);
    }
}

// ============ init padded-bucket cursors ============
__global__ __launch_bounds__(256) void k_initcur(int* __restrict__ bcur)
{
    if (threadIdx.x < NB2) bcur[threadIdx.x] = threadIdx.x * BCAP;
}

// ============ bucket edges into padded regions: (src<<9)|(dst&511) =========
__global__ __launch_bounds__(256) void k_pairs(const int* __restrict__ ei,
                                               int* __restrict__ bcur,
                                               int* __restrict__ pairs)
{
    __shared__ int lh[NB2];
    __shared__ int lbase[NB2];
    for (int i = threadIdx.x; i < NB2; i += 256) lh[i] = 0;
    __syncthreads();
    int base = blockIdx.x * PAIR_EPB;
    int myb[8], myr[8], myp[8];
#pragma unroll
    for (int t = 0; t < 8; t++) {
        int e = base + t * 256 + threadIdx.x;
        myb[t] = -1;
        if (e < N_EDGES) {
            int dst = ei[N_EDGES + e];
            int b = dst >> B2_SHIFT;
            myb[t] = b;
            myr[t] = atomicAdd(&lh[b], 1);
            myp[t] = (ei[e] << B2_SHIFT) | (dst & (BUCK_N - 1));
        }
    }
    __syncthreads();
    for (int i = threadIdx.x; i < NB2; i += 256)
        lbase[i] = lh[i] ? atomicAdd(&bcur[i], lh[i]) : 0;
    __syncthreads();
#pragma unroll
    for (int t = 0; t < 8; t++) {
        if (myb[t] >= 0) {
            int slot = lbase[myb[t]] + myr[t];
            if (slot < (myb[t] + 1) * BCAP)   // defensive (never expected)
                pairs[slot] = myp[t];
        }
    }
}

// ============ per-bucket CSR finalize: hist+scan+scatter; emits rs/re =======
__global__ __launch_bounds__(512) void k_sortb(const int* __restrict__ bcur,
                                               const int* __restrict__ pairs,
                                               int* __restrict__ sorted_src,
                                               int* __restrict__ rs,
                                               int* __restrict__ re)
{
    __shared__ int lcnt[BUCK_N];
    __shared__ int lofs[BUCK_N];
    int b = blockIdx.x;
    int beg = b * BCAP, end = bcur[b];
    lcnt[threadIdx.x] = 0;
    __syncthreads();
    for (int i = beg + threadIdx.x; i < end; i += 512)
        atomicAdd(&lcnt[pairs[i] & (BUCK_N - 1)], 1);
    __syncthreads();
    int v = lcnt[threadIdx.x];
    lofs[threadIdx.x] = v;
    __syncthreads();
    for (int off = 1; off < BUCK_N; off <<= 1) {
        int t = (threadIdx.x >= off) ? lofs[threadIdx.x - off] : 0;
        __syncthreads();
        lofs[threadIdx.x] += t;
        __syncthreads();
    }
    int excl = lofs[threadIdx.x] - v;
    int n = (b << B2_SHIFT) + threadIdx.x;
    if (n < N_NODES) { rs[n] = beg + excl; re[n] = beg + excl + v; }
    lcnt[threadIdx.x] = excl;
    __syncthreads();
    for (int i = beg + threadIdx.x; i < end; i += 512) {
        int p = pairs[i];
        int idx = atomicAdd(&lcnt[p & (BUCK_N - 1)], 1);
        sorted_src[beg + idx] = p >> B2_SHIFT;
    }
}

// ============ agg1: 32 lanes/node, bf16 gather, bf16 output ============
__global__ __launch_bounds__(256) void k_agg1(const int* __restrict__ rs,
                                              const int* __restrict__ re,
                                              const int* __restrict__ sorted_src,
                                              const unsigned* __restrict__ xh,
                                              unsigned* __restrict__ agg1h)
{
    int node = blockIdx.x * 8 + (threadIdx.x >> 5);
    if (node >= N_NODES) return;
    int d2 = threadIdx.x & 31;       // dims 2*d2, 2*d2+1
    int beg = rs[node], end = re[node];
    float a0 = 0.f, a1 = 0.f, b0 = 0.f, b1 = 0.f;
    int idx = beg;
    for (; idx + 4 <= end; idx += 4) {
        int s0 = sorted_src[idx], s1 = sorted_src[idx + 1];
        int s2 = sorted_src[idx + 2], s3 = sorted_src[idx + 3];
        unsigned p0 = xh[(size_t)s0 * 32 + d2];
        unsigned p1 = xh[(size_t)s1 * 32 + d2];
        unsigned p2 = xh[(size_t)s2 * 32 + d2];
        unsigned p3 = xh[(size_t)s3 * 32 + d2];
        a0 += lo16(p0) + lo16(p1);  a1 += hi16(p0) + hi16(p1);
        b0 += lo16(p2) + lo16(p3);  b1 += hi16(p2) + hi16(p3);
    }
    for (; idx < end; idx++) {
        unsigned p = xh[(size_t)sorted_src[idx] * 32 + d2];
        a0 += lo16(p);  a1 += hi16(p);
    }
    agg1h[(size_t)node * 32 + d2] = pack2(a0 + b0, a1 + b1);
}

// ============ node transform via MFMA: one wave per 16-node tile ============
// Layer 1: D[16n x 64j] = [agg1h | xh][16 x 128k] @ [W1l;W1r][128k x 64j]
//   (mean/self parts kept in separate accumulators; deg-scale applied in fp32)
// Layer 2: [16 x 64h] @ [W2l|W2r][64k x 64j] -> t2 (j<32, bf16) / t3 (j>=32).
// h routes D-layout -> A-layout through per-wave LDS (m120-verified pattern).
#define TPW 2     // tiles per wave
#define NTILE ((N_NODES + 15) / 16)                    // 6250
#define NODE_BLOCKS (((NTILE + TPW - 1) / TPW + 3) / 4)  // 782
__global__ __launch_bounds__(256) void k_node_mfma(
    const unsigned* __restrict__ xh, const unsigned* __restrict__ agg1h,
    const int* __restrict__ rs, const int* __restrict__ re,
    const float* __restrict__ W1l, const float* __restrict__ b1l,
    const float* __restrict__ W1r, const float* __restrict__ W2l,
    const float* __restrict__ W2r,
    unsigned* __restrict__ t2h, float* __restrict__ t3)
{
    __shared__ uint4 sWF[24 * 64];        // weight B-fragments, 24 KB
    __shared__ float sH[4][16 * 68];      // per-wave h buffer (pad 68)
    __shared__ float sT[4][16 * 44];      // per-wave t2 stage (pad 44)

    // ---- build B-fragments: frag f, lane l holds B[k0..k0+7][j] ----
    for (int s = threadIdx.x; s < 1536; s += 256) {
        int f = s >> 6, l = s & 63;
        int m = l & 15, q = l >> 4;
        float w[8];
        if (f < 16) {                     // B1 = [W1l(k<64); W1r(k>=64)]
            int jt = f >> 2, ks = f & 3;
            int j = jt * 16 + m;
            int k0 = ks * 32 + q * 8;
#pragma unroll
            for (int i = 0; i < 8; i++) {
                int kk = k0 + i;
                w[i] = (kk < 64) ? W1l[kk * 64 + j] : W1r[(kk - 64) * 64 + j];
            }
        } else {                          // B2 = [W2l | W2r]
            int f2 = f - 16;
            int jt = f2 >> 1, ks = f2 & 1;
            int j = jt * 16 + m;
            int k0 = ks * 32 + q * 8;
#pragma unroll
            for (int i = 0; i < 8; i++) {
                int kk = k0 + i;
                w[i] = (j < 32) ? W2l[kk * 32 + j] : W2r[kk * 32 + (j - 32)];
            }
        }
        sWF[f * 64 + l] = make_uint4(pack2(w[0], w[1]), pack2(w[2], w[3]),
                                     pack2(w[4], w[5]), pack2(w[6], w[7]));
    }
    __syncthreads();

    int w = threadIdx.x >> 6, lane = threadIdx.x & 63;
    int m = lane & 15, q = lane >> 4;

    // register-resident weight fragments
    bf16x8 WF1[4][4], WF2[4][2];
#pragma unroll
    for (int jt = 0; jt < 4; jt++) {
#pragma unroll
        for (int ks = 0; ks < 4; ks++)
            WF1[jt][ks] = __builtin_bit_cast(bf16x8, sWF[(jt * 4 + ks) * 64 + lane]);
#pragma unroll
        for (int ks = 0; ks < 2; ks++)
            WF2[jt][ks] = __builtin_bit_cast(bf16x8, sWF[(16 + jt * 2 + ks) * 64 + lane]);
    }
    float bias[4];
#pragma unroll
    for (int jt = 0; jt < 4; jt++) bias[jt] = b1l[jt * 16 + m];

    float* myH = &sH[w][0];
    float* myT = &sT[w][0];
    int gw = blockIdx.x * 4 + w;

    for (int t = 0; t < TPW; t++) {
        int tile = gw * TPW + t;
        if (tile >= NTILE) break;
        int nb = tile * 16;

        // A fragments: lane's node = nb+m, k-chunk = q*8
        int nc = nb + m; if (nc >= N_NODES) nc = N_NODES - 1;
        const uint4* arow = (const uint4*)(agg1h + (size_t)nc * 32);
        const uint4* xrow = (const uint4*)(xh + (size_t)nc * 32);
        bf16x8 AM[2], AX[2];
        AM[0] = __builtin_bit_cast(bf16x8, arow[q]);
        AM[1] = __builtin_bit_cast(bf16x8, arow[4 + q]);
        AX[0] = __builtin_bit_cast(bf16x8, xrow[q]);
        AX[1] = __builtin_bit_cast(bf16x8, xrow[4 + q]);

        // per-output-row deg scale (D row = q*4 + r)
        float invr[4];
#pragma unroll
        for (int r = 0; r < 4; r++) {
            int nn = nb + q * 4 + r;
            int nc2 = (nn < N_NODES) ? nn : 0;
            invr[r] = 1.0f / fmaxf((float)(re[nc2] - rs[nc2]), 1.0f);
        }

        // ---- layer 1 ----
#pragma unroll
        for (int jt = 0; jt < 4; jt++) {
            f32x4 aM = {0.f, 0.f, 0.f, 0.f}, aX = {0.f, 0.f, 0.f, 0.f};
            aM = __builtin_amdgcn_mfma_f32_16x16x32_bf16(AM[0], WF1[jt][0], aM, 0, 0, 0);
            aM = __builtin_amdgcn_mfma_f32_16x16x32_bf16(AM[1], WF1[jt][1], aM, 0, 0, 0);
            aX = __builtin_amdgcn_mfma_f32_16x16x32_bf16(AX[0], WF1[jt][2], aX, 0, 0, 0);
            aX = __builtin_amdgcn_mfma_f32_16x16x32_bf16(AX[1], WF1[jt][3], aX, 0, 0, 0);
#pragma unroll
            for (int r = 0; r < 4; r++) {
                float hv = fmaxf(aM[r] * invr[r] + aX[r] + bias[jt], 0.0f);
                myH[(q * 4 + r) * 68 + jt * 16 + m] = hv;   // [node][j]
            }
        }
        // wave-synchronous LDS round-trip (same wave writes then reads)

        // ---- h -> A-layout fragments ----
        bf16x8 A2[2];
#pragma unroll
        for (int ks = 0; ks < 2; ks++) {
            const float* p = &myH[m * 68 + ks * 32 + q * 8];
            float4 v0 = *(const float4*)p;
            float4 v1 = *(const float4*)(p + 4);
            uint4 u = make_uint4(pack2(v0.x, v0.y), pack2(v0.z, v0.w),
                                 pack2(v1.x, v1.y), pack2(v1.z, v1.w));
            A2[ks] = __builtin_bit_cast(bf16x8, u);
        }

        // ---- layer 2 ----
#pragma unroll
        for (int jt = 0; jt < 4; jt++) {
            f32x4 acc = {0.f, 0.f, 0.f, 0.f};
            acc = __builtin_amdgcn_mfma_f32_16x16x32_bf16(A2[0], WF2[jt][0], acc, 0, 0, 0);
            acc = __builtin_amdgcn_mfma_f32_16x16x32_bf16(A2[1], WF2[jt][1], acc, 0, 0, 0);
            if (jt < 2) {
#pragma unroll
                for (int r = 0; r < 4; r++)
                    myT[(q * 4 + r) * 44 + jt * 16 + m] = acc[r];
            } else {
#pragma unroll
                for (int r = 0; r < 4; r++) {
                    int nn = nb + q * 4 + r;
                    if (nn < N_NODES)
                        t3[(size_t)nn * 32 + (jt - 2) * 16 + m] = acc[r];
                }
            }
        }

        // ---- pack t2 -> bf16 global (4 lanes per node) ----
        int ni = lane >> 2, u4g = lane & 3;
        const float* tp = &myT[ni * 44 + u4g * 8];
        float4 a = *(const float4*)tp;
        float4 b = *(const float4*)(tp + 4);
        if (nb + ni < N_NODES) {
            uint4 o = make_uint4(pack2(a.x, a.y), pack2(a.z, a.w),
                                 pack2(b.x, b.y), pack2(b.z, b.w));
            *(uint4*)(t2h + (size_t)(nb + ni) * 16 + u4g * 4) = o;
        }
    }
}

// ============ agg2 + output: 16 lanes/node, bf16 gather (64 B/edge) ========
__global__ __launch_bounds__(256) void k_agg2out(
    const int* __restrict__ rs, const int* __restrict__ re,
    const int* __restrict__ sorted_src,
    const unsigned* __restrict__ t2h, const float* __restrict__ t3,
    const float* __restrict__ b2l, float* __restrict__ out)
{
    int node = blockIdx.x * 16 + (threadIdx.x >> 4);
    if (node >= N_NODES) return;
    int d2 = threadIdx.x & 15;       // dims 2*d2, 2*d2+1
    int beg = rs[node], end = re[node];
    float a0 = 0.f, a1 = 0.f, b0 = 0.f, b1 = 0.f;
    int idx = beg;
    for (; idx + 4 <= end; idx += 4) {
        int s0 = sorted_src[idx], s1 = sorted_src[idx + 1];
        int s2 = sorted_src[idx + 2], s3 = sorted_src[idx + 3];
        unsigned p0 = t2h[(size_t)s0 * 16 + d2];
        unsigned p1 = t2h[(size_t)s1 * 16 + d2];
        unsigned p2 = t2h[(size_t)s2 * 16 + d2];
        unsigned p3 = t2h[(size_t)s3 * 16 + d2];
        a0 += lo16(p0) + lo16(p1);  a1 += hi16(p0) + hi16(p1);
        b0 += lo16(p2) + lo16(p3);  b1 += hi16(p2) + hi16(p3);
    }
    for (; idx < end; idx++) {
        unsigned p = t2h[(size_t)sorted_src[idx] * 16 + d2];
        a0 += lo16(p);  a1 += hi16(p);
    }
    float inv = 1.0f / fmaxf((float)(end - beg), 1.0f);
    float2 tv = ((const float2*)(t3 + (size_t)node * 32))[d2];
    float2 bv = ((const float2*)b2l)[d2];
    ((float2*)(out + (size_t)node * 32))[d2] =
        make_float2((a0 + b0) * inv + tv.x + bv.x,
                    (a1 + b1) * inv + tv.y + bv.y);
}

extern "C" void kernel_launch(void* const* d_in, const int* in_sizes, int n_in,
                              void* d_out, int out_size, void* d_ws, size_t ws_size,
                              hipStream_t stream) {
    const float* x   = (const float*)d_in[0];
    const int*   ei  = (const int*)d_in[1];
    const float* W1l = (const float*)d_in[2];
    const float* b1l = (const float*)d_in[3];
    const float* W1r = (const float*)d_in[4];
    const float* W2l = (const float*)d_in[5];
    const float* b2l = (const float*)d_in[6];
    const float* W2r = (const float*)d_in[7];
    float* out = (float*)d_out;

    const size_t N = N_NODES;
    // 64 B-aligned workspace layout
    int* wsi = (int*)d_ws;
    int*      pairs      = wsi;                          // NB2*BCAP = 1806336
    int*      sorted_src = wsi + 1806336;                // NB2*BCAP
    int*      bcur       = wsi + 3612672;                // 256
    int*      rs         = wsi + 3612928;                // N
    int*      re         = wsi + 3712928;                // N
    unsigned* xh         = (unsigned*)(wsi + 3812928);   // 32N
    unsigned* t2h        = xh + 32 * N;                  // 16N
    unsigned* agg1h      = t2h + 16 * N;                 // 32N
    float*    t3         = (float*)(agg1h + 32 * N);     // 32N
    // total ~= 15.0M ints ~= 60 MB

    k_cast   <<<(int)((N * 32 + 255) / 256), 256, 0, stream>>>(x, xh);
    k_initcur<<<1, 256, 0, stream>>>(bcur);
    k_pairs  <<<PAIR_BLOCKS, 256, 0, stream>>>(ei, bcur, pairs);
    k_sortb  <<<NB2, 512, 0, stream>>>(bcur, pairs, sorted_src, rs, re);

    k_agg1     <<<(int)((N + 7) / 8), 256, 0, stream>>>(rs, re, sorted_src, xh, agg1h);
    k_node_mfma<<<NODE_BLOCKS, 256, 0, stream>>>(xh, agg1h, rs, re,
                                                 W1l, b1l, W1r, W2l, W2r, t2h, t3);
    k_agg2out  <<<(int)((N + 15) / 16), 256, 0, stream>>>(rs, re, sorted_src,
                                                 t2h, t3, b2l, out);
}

// Round 14
// 208.106 us; speedup vs baseline: 6.7170x; 1.0663x over previous
//
#include <hip/hip_runtime.h>

#define N_NODES 100000
#define N_EDGES 1600000
#define B2_SHIFT 9
#define BUCK_N (1 << B2_SHIFT)                   // 512 nodes per bucket
#define NB2 ((N_NODES + BUCK_N - 1) >> B2_SHIFT) // 196 buckets
#define BCAP 9216                                // padded bucket capacity (avg 8163)
#define PAIR_EPB 4096
#define PAIR_BLOCKS ((N_EDGES + PAIR_EPB - 1) / PAIR_EPB)   // 391

typedef __attribute__((ext_vector_type(8))) short bf16x8;
typedef __attribute__((ext_vector_type(4))) float f32x4;

// ---- bf16 pack/unpack helpers (RNE) ----
__device__ __forceinline__ unsigned pack2(float a, float b) {
    unsigned ua = __float_as_uint(a), ub = __float_as_uint(b);
    ua = (ua + 0x7FFFu + ((ua >> 16) & 1u)) >> 16;
    ub = (ub + 0x7FFFu + ((ub >> 16) & 1u)) >> 16;
    return ua | (ub << 16);
}
__device__ __forceinline__ float lo16(unsigned u) { return __uint_as_float(u << 16); }
__device__ __forceinline__ float hi16(unsigned u) { return __uint_as_float(u & 0xFFFF0000u); }

// ============ cast x -> packed bf16 (dims pair-packed) ============
__global__ __launch_bounds__(256) void k_cast(const float* __restrict__ x,
                                              unsigned* __restrict__ xh)
{
    int i = blockIdx.x * 256 + threadIdx.x;   // over 32N uints
    if (i < N_NODES * 32) {
        float2 v = ((const float2*)x)[i];
        xh[i] = pack2(v.x, v.y);
    }
}

// ============ init padded-bucket cursors ============
__global__ __launch_bounds__(256) void k_initcur(int* __restrict__ bcur)
{
    if (threadIdx.x < NB2) bcur[threadIdx.x] = threadIdx.x * BCAP;
}

// ============ bucket edges into padded regions: (src<<9)|(dst&511) =========
// 16 edges/thread; LDS rank counters replicated per wave-pair to halve
// contention; one global flush atomic per (bucket, block).
__global__ __launch_bounds__(256) void k_pairs(const int* __restrict__ ei,
                                               int* __restrict__ bcur,
                                               int* __restrict__ pairs)
{
    __shared__ int lh[2][NB2];
    __shared__ int lb[2][NB2];
    for (int i = threadIdx.x; i < NB2; i += 256) { lh[0][i] = 0; lh[1][i] = 0; }
    __syncthreads();
    int cp = (threadIdx.x >> 6) & 1;          // wave-pair copy
    int base = blockIdx.x * PAIR_EPB;
    int myb[16], myr[16], myp[16];
#pragma unroll
    for (int t = 0; t < 16; t++) {
        int e = base + t * 256 + threadIdx.x;
        myb[t] = -1;
        if (e < N_EDGES) {
            int dst = ei[N_EDGES + e];
            int b = dst >> B2_SHIFT;
            myb[t] = b;
            myr[t] = atomicAdd(&lh[cp][b], 1);
            myp[t] = (ei[e] << B2_SHIFT) | (dst & (BUCK_N - 1));
        }
    }
    __syncthreads();
    for (int i = threadIdx.x; i < NB2; i += 256) {
        int c0 = lh[0][i], c1 = lh[1][i];
        int basei = (c0 + c1) ? atomicAdd(&bcur[i], c0 + c1) : 0;
        lb[0][i] = basei;
        lb[1][i] = basei + c0;
    }
    __syncthreads();
#pragma unroll
    for (int t = 0; t < 16; t++) {
        if (myb[t] >= 0) {
            int slot = lb[cp][myb[t]] + myr[t];
            if (slot < (myb[t] + 1) * BCAP)   // defensive (never expected)
                pairs[slot] = myp[t];
        }
    }
}

// ============ per-bucket CSR finalize: hist + wave-scan + scatter ==========
__global__ __launch_bounds__(512) void k_sortb(const int* __restrict__ bcur,
                                               const int* __restrict__ pairs,
                                               int* __restrict__ sorted_src,
                                               int* __restrict__ rs,
                                               int* __restrict__ re)
{
    __shared__ int lcnt[BUCK_N];
    __shared__ int wtot[8];
    int b = blockIdx.x;
    int beg = b * BCAP, end = bcur[b];
    lcnt[threadIdx.x] = 0;
    __syncthreads();
    for (int i = beg + threadIdx.x; i < end; i += 512)
        atomicAdd(&lcnt[pairs[i] & (BUCK_N - 1)], 1);
    __syncthreads();
    int v = lcnt[threadIdx.x];
    // wave-level inclusive scan (64 lanes, no barriers)
    int lane = threadIdx.x & 63, wid = threadIdx.x >> 6;
    int s = v;
#pragma unroll
    for (int off = 1; off < 64; off <<= 1) {
        int t = __shfl_up(s, off);
        if (lane >= off) s += t;
    }
    if (lane == 63) wtot[wid] = s;
    __syncthreads();
    // cross-wave exclusive offset (8 values, done redundantly per thread)
    int woff = 0;
#pragma unroll
    for (int k = 0; k < 8; k++) woff += (k < wid) ? wtot[k] : 0;
    int excl = woff + s - v;
    int n = (b << B2_SHIFT) + threadIdx.x;
    if (n < N_NODES) { rs[n] = beg + excl; re[n] = beg + excl + v; }
    __syncthreads();
    lcnt[threadIdx.x] = beg + excl;           // global write cursor
    __syncthreads();
    for (int i = beg + threadIdx.x; i < end; i += 512) {
        int p = pairs[i];
        int idx = atomicAdd(&lcnt[p & (BUCK_N - 1)], 1);
        sorted_src[idx] = p >> B2_SHIFT;
    }
}

// ============ agg1: 32 lanes/node, bf16 gather, 8-deep unroll ============
__global__ __launch_bounds__(256) void k_agg1(const int* __restrict__ rs,
                                              const int* __restrict__ re,
                                              const int* __restrict__ sorted_src,
                                              const unsigned* __restrict__ xh,
                                              unsigned* __restrict__ agg1h)
{
    int node = blockIdx.x * 8 + (threadIdx.x >> 5);
    if (node >= N_NODES) return;
    int d2 = threadIdx.x & 31;       // dims 2*d2, 2*d2+1
    int beg = rs[node], end = re[node];
    float a0 = 0.f, a1 = 0.f, b0 = 0.f, b1 = 0.f;
    int idx = beg;
    for (; idx + 8 <= end; idx += 8) {
        int s0 = sorted_src[idx + 0], s1 = sorted_src[idx + 1];
        int s2 = sorted_src[idx + 2], s3 = sorted_src[idx + 3];
        int s4 = sorted_src[idx + 4], s5 = sorted_src[idx + 5];
        int s6 = sorted_src[idx + 6], s7 = sorted_src[idx + 7];
        unsigned p0 = xh[(size_t)s0 * 32 + d2];
        unsigned p1 = xh[(size_t)s1 * 32 + d2];
        unsigned p2 = xh[(size_t)s2 * 32 + d2];
        unsigned p3 = xh[(size_t)s3 * 32 + d2];
        unsigned p4 = xh[(size_t)s4 * 32 + d2];
        unsigned p5 = xh[(size_t)s5 * 32 + d2];
        unsigned p6 = xh[(size_t)s6 * 32 + d2];
        unsigned p7 = xh[(size_t)s7 * 32 + d2];
        a0 += lo16(p0) + lo16(p1);  a1 += hi16(p0) + hi16(p1);
        b0 += lo16(p2) + lo16(p3);  b1 += hi16(p2) + hi16(p3);
        a0 += lo16(p4) + lo16(p5);  a1 += hi16(p4) + hi16(p5);
        b0 += lo16(p6) + lo16(p7);  b1 += hi16(p6) + hi16(p7);
    }
    for (; idx + 2 <= end; idx += 2) {
        int s0 = sorted_src[idx], s1 = sorted_src[idx + 1];
        unsigned p0 = xh[(size_t)s0 * 32 + d2];
        unsigned p1 = xh[(size_t)s1 * 32 + d2];
        a0 += lo16(p0) + lo16(p1);  a1 += hi16(p0) + hi16(p1);
    }
    if (idx < end) {
        unsigned p = xh[(size_t)sorted_src[idx] * 32 + d2];
        a0 += lo16(p);  a1 += hi16(p);
    }
    agg1h[(size_t)node * 32 + d2] = pack2(a0 + b0, a1 + b1);
}

// ============ node transform via MFMA: one wave per 16-node tile ============
#define TPW 2     // tiles per wave
#define NTILE ((N_NODES + 15) / 16)                    // 6250
#define NODE_BLOCKS (((NTILE + TPW - 1) / TPW + 3) / 4)  // 782
__global__ __launch_bounds__(256) void k_node_mfma(
    const unsigned* __restrict__ xh, const unsigned* __restrict__ agg1h,
    const int* __restrict__ rs, const int* __restrict__ re,
    const float* __restrict__ W1l, const float* __restrict__ b1l,
    const float* __restrict__ W1r, const float* __restrict__ W2l,
    const float* __restrict__ W2r,
    unsigned* __restrict__ t2h, float* __restrict__ t3)
{
    __shared__ uint4 sWF[24 * 64];        // weight B-fragments, 24 KB
    __shared__ float sH[4][16 * 68];      // per-wave h buffer (pad 68)
    __shared__ float sT[4][16 * 44];      // per-wave t2 stage (pad 44)

    // ---- build B-fragments: frag f, lane l holds B[k0..k0+7][j] ----
    for (int s = threadIdx.x; s < 1536; s += 256) {
        int f = s >> 6, l = s & 63;
        int m = l & 15, q = l >> 4;
        float w[8];
        if (f < 16) {                     // B1 = [W1l(k<64); W1r(k>=64)]
            int jt = f >> 2, ks = f & 3;
            int j = jt * 16 + m;
            int k0 = ks * 32 + q * 8;
#pragma unroll
            for (int i = 0; i < 8; i++) {
                int kk = k0 + i;
                w[i] = (kk < 64) ? W1l[kk * 64 + j] : W1r[(kk - 64) * 64 + j];
            }
        } else {                          // B2 = [W2l | W2r]
            int f2 = f - 16;
            int jt = f2 >> 1, ks = f2 & 1;
            int j = jt * 16 + m;
            int k0 = ks * 32 + q * 8;
#pragma unroll
            for (int i = 0; i < 8; i++) {
                int kk = k0 + i;
                w[i] = (j < 32) ? W2l[kk * 32 + j] : W2r[kk * 32 + (j - 32)];
            }
        }
        sWF[f * 64 + l] = make_uint4(pack2(w[0], w[1]), pack2(w[2], w[3]),
                                     pack2(w[4], w[5]), pack2(w[6], w[7]));
    }
    __syncthreads();

    int w = threadIdx.x >> 6, lane = threadIdx.x & 63;
    int m = lane & 15, q = lane >> 4;

    bf16x8 WF1[4][4], WF2[4][2];
#pragma unroll
    for (int jt = 0; jt < 4; jt++) {
#pragma unroll
        for (int ks = 0; ks < 4; ks++)
            WF1[jt][ks] = __builtin_bit_cast(bf16x8, sWF[(jt * 4 + ks) * 64 + lane]);
#pragma unroll
        for (int ks = 0; ks < 2; ks++)
            WF2[jt][ks] = __builtin_bit_cast(bf16x8, sWF[(16 + jt * 2 + ks) * 64 + lane]);
    }
    float bias[4];
#pragma unroll
    for (int jt = 0; jt < 4; jt++) bias[jt] = b1l[jt * 16 + m];

    float* myH = &sH[w][0];
    float* myT = &sT[w][0];
    int gw = blockIdx.x * 4 + w;

    for (int t = 0; t < TPW; t++) {
        int tile = gw * TPW + t;
        if (tile >= NTILE) break;
        int nb = tile * 16;

        int nc = nb + m; if (nc >= N_NODES) nc = N_NODES - 1;
        const uint4* arow = (const uint4*)(agg1h + (size_t)nc * 32);
        const uint4* xrow = (const uint4*)(xh + (size_t)nc * 32);
        bf16x8 AM[2], AX[2];
        AM[0] = __builtin_bit_cast(bf16x8, arow[q]);
        AM[1] = __builtin_bit_cast(bf16x8, arow[4 + q]);
        AX[0] = __builtin_bit_cast(bf16x8, xrow[q]);
        AX[1] = __builtin_bit_cast(bf16x8, xrow[4 + q]);

        float invr[4];
#pragma unroll
        for (int r = 0; r < 4; r++) {
            int nn = nb + q * 4 + r;
            int nc2 = (nn < N_NODES) ? nn : 0;
            invr[r] = 1.0f / fmaxf((float)(re[nc2] - rs[nc2]), 1.0f);
        }

        // ---- layer 1 ----
#pragma unroll
        for (int jt = 0; jt < 4; jt++) {
            f32x4 aM = {0.f, 0.f, 0.f, 0.f}, aX = {0.f, 0.f, 0.f, 0.f};
            aM = __builtin_amdgcn_mfma_f32_16x16x32_bf16(AM[0], WF1[jt][0], aM, 0, 0, 0);
            aM = __builtin_amdgcn_mfma_f32_16x16x32_bf16(AM[1], WF1[jt][1], aM, 0, 0, 0);
            aX = __builtin_amdgcn_mfma_f32_16x16x32_bf16(AX[0], WF1[jt][2], aX, 0, 0, 0);
            aX = __builtin_amdgcn_mfma_f32_16x16x32_bf16(AX[1], WF1[jt][3], aX, 0, 0, 0);
#pragma unroll
            for (int r = 0; r < 4; r++) {
                float hv = fmaxf(aM[r] * invr[r] + aX[r] + bias[jt], 0.0f);
                myH[(q * 4 + r) * 68 + jt * 16 + m] = hv;   // [node][j]
            }
        }
        // wave-synchronous LDS round-trip (same wave writes then reads)

        bf16x8 A2[2];
#pragma unroll
        for (int ks = 0; ks < 2; ks++) {
            const float* p = &myH[m * 68 + ks * 32 + q * 8];
            float4 v0 = *(const float4*)p;
            float4 v1 = *(const float4*)(p + 4);
            uint4 u = make_uint4(pack2(v0.x, v0.y), pack2(v0.z, v0.w),
                                 pack2(v1.x, v1.y), pack2(v1.z, v1.w));
            A2[ks] = __builtin_bit_cast(bf16x8, u);
        }

        // ---- layer 2 ----
#pragma unroll
        for (int jt = 0; jt < 4; jt++) {
            f32x4 acc = {0.f, 0.f, 0.f, 0.f};
            acc = __builtin_amdgcn_mfma_f32_16x16x32_bf16(A2[0], WF2[jt][0], acc, 0, 0, 0);
            acc = __builtin_amdgcn_mfma_f32_16x16x32_bf16(A2[1], WF2[jt][1], acc, 0, 0, 0);
            if (jt < 2) {
#pragma unroll
                for (int r = 0; r < 4; r++)
                    myT[(q * 4 + r) * 44 + jt * 16 + m] = acc[r];
            } else {
#pragma unroll
                for (int r = 0; r < 4; r++) {
                    int nn = nb + q * 4 + r;
                    if (nn < N_NODES)
                        t3[(size_t)nn * 32 + (jt - 2) * 16 + m] = acc[r];
                }
            }
        }

        // ---- pack t2 -> bf16 global (4 lanes per node) ----
        int ni = lane >> 2, u4g = lane & 3;
        const float* tp = &myT[ni * 44 + u4g * 8];
        float4 a = *(const float4*)tp;
        float4 b = *(const float4*)(tp + 4);
        if (nb + ni < N_NODES) {
            uint4 o = make_uint4(pack2(a.x, a.y), pack2(a.z, a.w),
                                 pack2(b.x, b.y), pack2(b.z, b.w));
            *(uint4*)(t2h + (size_t)(nb + ni) * 16 + u4g * 4) = o;
        }
    }
}

// ============ agg2 + output: 16 lanes/node, bf16 gather, 8-deep unroll =====
__global__ __launch_bounds__(256) void k_agg2out(
    const int* __restrict__ rs, const int* __restrict__ re,
    const int* __restrict__ sorted_src,
    const unsigned* __restrict__ t2h, const float* __restrict__ t3,
    const float* __restrict__ b2l, float* __restrict__ out)
{
    int node = blockIdx.x * 16 + (threadIdx.x >> 4);
    if (node >= N_NODES) return;
    int d2 = threadIdx.x & 15;       // dims 2*d2, 2*d2+1
    int beg = rs[node], end = re[node];
    float a0 = 0.f, a1 = 0.f, b0 = 0.f, b1 = 0.f;
    int idx = beg;
    for (; idx + 8 <= end; idx += 8) {
        int s0 = sorted_src[idx + 0], s1 = sorted_src[idx + 1];
        int s2 = sorted_src[idx + 2], s3 = sorted_src[idx + 3];
        int s4 = sorted_src[idx + 4], s5 = sorted_src[idx + 5];
        int s6 = sorted_src[idx + 6], s7 = sorted_src[idx + 7];
        unsigned p0 = t2h[(size_t)s0 * 16 + d2];
        unsigned p1 = t2h[(size_t)s1 * 16 + d2];
        unsigned p2 = t2h[(size_t)s2 * 16 + d2];
        unsigned p3 = t2h[(size_t)s3 * 16 + d2];
        unsigned p4 = t2h[(size_t)s4 * 16 + d2];
        unsigned p5 = t2h[(size_t)s5 * 16 + d2];
        unsigned p6 = t2h[(size_t)s6 * 16 + d2];
        unsigned p7 = t2h[(size_t)s7 * 16 + d2];
        a0 += lo16(p0) + lo16(p1);  a1 += hi16(p0) + hi16(p1);
        b0 += lo16(p2) + lo16(p3);  b1 += hi16(p2) + hi16(p3);
        a0 += lo16(p4) + lo16(p5);  a1 += hi16(p4) + hi16(p5);
        b0 += lo16(p6) + lo16(p7);  b1 += hi16(p6) + hi16(p7);
    }
    for (; idx + 2 <= end; idx += 2) {
        int s0 = sorted_src[idx], s1 = sorted_src[idx + 1];
        unsigned p0 = t2h[(size_t)s0 * 16 + d2];
        unsigned p1 = t2h[(size_t)s1 * 16 + d2];
        a0 += lo16(p0) + lo16(p1);  a1 += hi16(p0) + hi16(p1);
    }
    if (idx < end) {
        unsigned p = t2h[(size_t)sorted_src[idx] * 16 + d2];
        a0 += lo16(p);  a1 += hi16(p);
    }
    float inv = 1.0f / fmaxf((float)(end - beg), 1.0f);
    float2 tv = ((const float2*)(t3 + (size_t)node * 32))[d2];
    float2 bv = ((const float2*)b2l)[d2];
    ((float2*)(out + (size_t)node * 32))[d2] =
        make_float2((a0 + b0) * inv + tv.x + bv.x,
                    (a1 + b1) * inv + tv.y + bv.y);
}

extern "C" void kernel_launch(void* const* d_in, const int* in_sizes, int n_in,
                              void* d_out, int out_size, void* d_ws, size_t ws_size,
                              hipStream_t stream) {
    const float* x   = (const float*)d_in[0];
    const int*   ei  = (const int*)d_in[1];
    const float* W1l = (const float*)d_in[2];
    const float* b1l = (const float*)d_in[3];
    const float* W1r = (const float*)d_in[4];
    const float* W2l = (const float*)d_in[5];
    const float* b2l = (const float*)d_in[6];
    const float* W2r = (const float*)d_in[7];
    float* out = (float*)d_out;

    const size_t N = N_NODES;
    // 64 B-aligned workspace layout
    int* wsi = (int*)d_ws;
    int*      pairs      = wsi;                          // NB2*BCAP = 1806336
    int*      sorted_src = wsi + 1806336;                // NB2*BCAP
    int*      bcur       = wsi + 3612672;                // 256
    int*      rs         = wsi + 3612928;                // N
    int*      re         = wsi + 3712928;                // N
    unsigned* xh         = (unsigned*)(wsi + 3812928);   // 32N
    unsigned* t2h        = xh + 32 * N;                  // 16N
    unsigned* agg1h      = t2h + 16 * N;                 // 32N
    float*    t3         = (float*)(agg1h + 32 * N);     // 32N
    // total ~= 15.0M ints ~= 60 MB

    k_cast   <<<(int)((N * 32 + 255) / 256), 256, 0, stream>>>(x, xh);
    k_initcur<<<1, 256, 0, stream>>>(bcur);
    k_pairs  <<<PAIR_BLOCKS, 256, 0, stream>>>(ei, bcur, pairs);
    k_sortb  <<<NB2, 512, 0, stream>>>(bcur, pairs, sorted_src, rs, re);

    k_agg1     <<<(int)((N + 7) / 8), 256, 0, stream>>>(rs, re, sorted_src, xh, agg1h);
    k_node_mfma<<<NODE_BLOCKS, 256, 0, stream>>>(xh, agg1h, rs, re,
                                                 W1l, b1l, W1r, W2l, W2r, t2h, t3);
    k_agg2out  <<<(int)((N + 15) / 16), 256, 0, stream>>>(rs, re, sorted_src,
                                                 t2h, t3, b2l, out);
}